// Round 7
// baseline (550.111 us; speedup 1.0000x reference)
//
#include <hip/hip_runtime.h>
#include <stdint.h>

#define S_ 2048
#define D_ 1024
#define H_ 16
#define DEP_ 64

typedef float f32x4 __attribute__((ext_vector_type(4)));
typedef __bf16 bf16x8 __attribute__((ext_vector_type(8)));

#define MFMA16(a,b,c) __builtin_amdgcn_mfma_f32_16x16x32_bf16((a),(b),(c),0,0,0)

// Output offsets (floats): (out, E, A, pw, attv, ba, avAp, Ep)
static constexpr size_t OFF_E    = 2097152ull;
static constexpr size_t OFF_A    = 69206016ull;
static constexpr size_t OFF_PW   = 69271552ull;
static constexpr size_t OFF_ATT  = 69271616ull;
static constexpr size_t OFF_BA   = 136380480ull;
static constexpr size_t OFF_AVAP = 136380481ull;
static constexpr size_t OFF_EP   = 136381505ull;

__device__ __forceinline__ short f2b(float f) {
  union { float f; uint32_t u; } c; c.f = f;
  uint32_t u = c.u;
  uint32_t r = (u + 0x7fffu + ((u >> 16) & 1u)) >> 16;
  return (short)(r & 0xffffu);
}
__device__ __forceinline__ float b2f(short s) {
  union { uint32_t u; float f; } c; c.u = ((uint32_t)(uint16_t)s) << 16;
  return c.f;
}
__device__ __forceinline__ void st4(float* p, f32x4 v) {
  *(f32x4*)p = v;
}

// ---------------- fused converts: inputs, proj weights, res weights ----------------
__global__ void k_cvt_all(const float* __restrict__ q, const float* __restrict__ k,
                          const float* __restrict__ v, const float* __restrict__ wq,
                          const float* __restrict__ wk, const float* __restrict__ wv,
                          const float* __restrict__ wo, const float* __restrict__ w1,
                          const float* __restrict__ w2, short* __restrict__ xbf,
                          short* __restrict__ wT, short* __restrict__ w1T,
                          short* __restrict__ w2T) {
  __shared__ float tile[64][65];
  int bid = blockIdx.x, t = threadIdx.x;
  if (bid < 6144) {
    int z = bid >> 11, bx = bid & 2047;
    const float* src = (z == 0) ? q : (z == 1) ? k : v;
    short* d = xbf + (size_t)z * (S_*D_);
    int i = (bx*256 + t)*4;
    float4 f = *(const float4*)(src + i);
    short4 o;
    o.x = f2b(f.x); o.y = f2b(f.y); o.z = f2b(f.z); o.w = f2b(f.w);
    *(short4*)(d + i) = o;
  } else if (bid < 7168) {
    int u = bid - 6144, z = u >> 8, tl = u & 255;
    int k0 = (tl >> 4)*64, n0 = (tl & 15)*64;
    const float* W = (z == 0) ? wq : (z == 1) ? wk : (z == 2) ? wv : wo;
    short* d = wT + (size_t)z * (D_*D_);
    for (int i = 0; i < 16; ++i) {
      int e = i*256 + t, r = e >> 6, c = e & 63;
      tile[r][c] = W[(size_t)(k0+r)*D_ + n0 + c];
    }
    __syncthreads();
    for (int i = 0; i < 16; ++i) {
      int e = i*256 + t, r = e >> 6, c = e & 63;
      d[(size_t)(n0+r)*D_ + k0 + c] = f2b(tile[c][r]);
    }
  } else {
    int u = bid - 7168, z = u >> 4, bx = u & 15;
    int l = z >> 1, which = z & 1;
    if (which == 0) {
      const float* src = w1 + (size_t)l*65536;
      short* d = w1T + (size_t)l*65536;
      int n0 = bx*64;
      for (int i = 0; i < 16; ++i) {
        int e = i*256 + t, r = e >> 6, c = e & 63;
        tile[r][c] = src[(size_t)r*1024 + n0 + c];
      }
      __syncthreads();
      for (int i = 0; i < 16; ++i) {
        int e = i*256 + t, r = e >> 6, c = e & 63;
        d[(size_t)(n0+r)*64 + c] = f2b(tile[c][r]);
      }
    } else {
      const float* src = w2 + (size_t)l*65536;
      short* d = w2T + (size_t)l*65536;
      int k0 = bx*64;
      for (int i = 0; i < 16; ++i) {
        int e = i*256 + t, r = e >> 6, c = e & 63;
        tile[r][c] = src[(size_t)(k0+r)*64 + c];
      }
      __syncthreads();
      for (int i = 0; i < 16; ++i) {
        int e = i*256 + t, r = e >> 6, c = e & 63;
        d[(size_t)r*1024 + k0 + c] = f2b(tile[c][r]);
      }
    }
  }
}

// ---------------- 128x128 bf16 GEMM: C = X @ WT^T + bias ----------------
// mode 0: write bf16 head-major; mode 2: X = X + X2 (bf16 sum), write f32 outf
__global__ __launch_bounds__(256) void k_gemm(
    const short* __restrict__ Xall, const short* __restrict__ X2,
    const short* __restrict__ WTall,
    const float* __restrict__ b0, const float* __restrict__ b1v,
    const float* __restrict__ b2v, short* __restrict__ dstall,
    float* __restrict__ outf, int mode) {
  __shared__ short As[128*72];
  __shared__ short Bs[128*72];
  int z = blockIdx.z;
  const short* X  = Xall + (size_t)z * (S_*D_);
  const short* WT = WTall + (size_t)z * (D_*D_);
  int m0 = blockIdx.x * 128, n0 = blockIdx.y * 128;
  int t = threadIdx.x, lane = t & 63;
  int wr = t >> 7, wc = (t >> 6) & 1;
  int rA = lane & 15, kg = lane >> 4;
  f32x4 acc[4][4] = {};
  for (int kt = 0; kt < 16; ++kt) {
#pragma unroll
    for (int i = 0; i < 4; ++i) {
      int cid = i*256 + t, row = cid >> 3, c = cid & 7;
      size_t xi = (size_t)(m0+row)*D_ + kt*64 + c*8;
      if (mode == 2) {
        union { int4 v; short s[8]; } a1, a2, o;
        a1.v = *(const int4*)&X[xi];
        a2.v = *(const int4*)&X2[xi];
#pragma unroll
        for (int j = 0; j < 8; ++j) o.s[j] = f2b(b2f(a1.s[j]) + b2f(a2.s[j]));
        *(int4*)&As[row*72 + c*8] = o.v;
      } else {
        *(int4*)&As[row*72 + c*8] = *(const int4*)&X[xi];
      }
      *(int4*)&Bs[row*72 + c*8] = *(const int4*)&WT[(size_t)(n0+row)*D_ + kt*64 + c*8];
    }
    __syncthreads();
#pragma unroll
    for (int kk = 0; kk < 2; ++kk) {
      bf16x8 a[4], b[4];
#pragma unroll
      for (int m = 0; m < 4; ++m)
        a[m] = *(const bf16x8*)&As[(wr*64 + m*16 + rA)*72 + kk*32 + kg*8];
#pragma unroll
      for (int n = 0; n < 4; ++n)
        b[n] = *(const bf16x8*)&Bs[(wc*64 + n*16 + rA)*72 + kk*32 + kg*8];
#pragma unroll
      for (int m = 0; m < 4; ++m)
#pragma unroll
        for (int n = 0; n < 4; ++n)
          acc[m][n] = MFMA16(a[m], b[n], acc[m][n]);
    }
    __syncthreads();
  }
  const float* bias = (mode != 0) ? b0 : (z == 0 ? b0 : (z == 1 ? b1v : b2v));
#pragma unroll
  for (int m = 0; m < 4; ++m) {
#pragma unroll
    for (int n = 0; n < 4; ++n) {
      int col = n0 + wc*64 + n*16 + rA;
      float bb = bias[col];
#pragma unroll
      for (int rr = 0; rr < 4; ++rr) {
        int row = m0 + wr*64 + m*16 + kg*4 + rr;
        float val = acc[m][n][rr] + bb;
        if (mode == 0) {
          int head = col >> 6, dd = col & 63;
          dstall[(size_t)z*(S_*D_) + ((size_t)head*S_ + row)*DEP_ + dd] = f2b(val);
        } else {
          outf[(size_t)row*D_ + col] = val;
        }
      }
    }
  }
}

// ---------------- bf16 transpose [h][S][64] -> [h][64][S] ----------------
__global__ void k_transpose(const short* __restrict__ qh, const short* __restrict__ vh,
                            short* __restrict__ qhT, short* __restrict__ vhT) {
  __shared__ short tile[64][68];
  const short* src = blockIdx.z ? vh : qh;
  short* dst = blockIdx.z ? vhT : qhT;
  int h = blockIdx.y, s0 = blockIdx.x * 64, t = threadIdx.x;
  for (int i = 0; i < 16; ++i) {
    int e = i*256 + t, r = e >> 6, c = e & 63;
    tile[r][c] = src[((size_t)h*S_ + s0 + r)*DEP_ + c];
  }
  __syncthreads();
  for (int i = 0; i < 16; ++i) {
    int e = i*256 + t, r = e >> 6, c = e & 63;
    dst[((size_t)h*DEP_ + r)*S_ + s0 + c] = tile[c][r];
  }
}

// ---------------- metric partial ----------------
__global__ __launch_bounds__(256) void k_metric_p(const short* __restrict__ qhT,
                                                  float* __restrict__ Apart) {
  __shared__ short qt[64*72];
  int kc = blockIdx.x, h = blockIdx.y, t = threadIdx.x, lane = t & 63;
  int wr = t >> 7, wc = (t >> 6) & 1;
  int rA = lane & 15, kg = lane >> 4;
  f32x4 acc[2][2] = {};
  for (int kt = 0; kt < 4; ++kt) {
#pragma unroll
    for (int i = 0; i < 2; ++i) {
      int cid = i*256 + t, row = cid >> 3, c = cid & 7;
      *(int4*)&qt[row*72 + c*8] =
        *(const int4*)&qhT[((size_t)h*DEP_ + row)*S_ + kc*256 + kt*64 + c*8];
    }
    __syncthreads();
#pragma unroll
    for (int kk = 0; kk < 2; ++kk) {
      bf16x8 a[2], b[2];
#pragma unroll
      for (int m = 0; m < 2; ++m)
        a[m] = *(const bf16x8*)&qt[(wr*32 + m*16 + rA)*72 + kk*32 + kg*8];
#pragma unroll
      for (int n = 0; n < 2; ++n)
        b[n] = *(const bf16x8*)&qt[(wc*32 + n*16 + rA)*72 + kk*32 + kg*8];
#pragma unroll
      for (int m = 0; m < 2; ++m)
#pragma unroll
        for (int n = 0; n < 2; ++n)
          acc[m][n] = MFMA16(a[m], b[n], acc[m][n]);
    }
    __syncthreads();
  }
#pragma unroll
  for (int m = 0; m < 2; ++m)
#pragma unroll
    for (int n = 0; n < 2; ++n)
#pragma unroll
      for (int rr = 0; rr < 4; ++rr) {
        int row = wr*32 + m*16 + kg*4 + rr, col = wc*32 + n*16 + rA;
        Apart[((size_t)(kc*16 + h))*4096 + row*64 + col] = acc[m][n][rr];
      }
}

// ---------------- fused res stack: metric reduce + 2x(d1+d2+LN) + avAp ----------------
__global__ __launch_bounds__(512) void k_res(
    const float* __restrict__ Apart, const short* __restrict__ w1T,
    const float* __restrict__ b1, const short* __restrict__ w2T,
    const float* __restrict__ b2, const float* __restrict__ gl,
    const float* __restrict__ bel, const float* __restrict__ pwv,
    const float* __restrict__ av, const float* __restrict__ bav,
    float* __restrict__ avApW, float* __restrict__ outB) {
  __shared__ float Af[64][68];     // current activation (residual source)
  __shared__ short Afb[64][72];    // bf16 mirror for MFMA A-op
  __shared__ short hdP[64*520];    // hd bf16 [64][520] / d2 partials f32 [4][64][65]
  __shared__ float red[8][64];
  int h = blockIdx.x, t = threadIdx.x;
  int lane = t & 63, w = t >> 6;
  int rA = lane & 15, kg = lane >> 4;
  // metric reduce: Af = sum_kc Apart[kc][h]
#pragma unroll
  for (int i = 0; i < 2; ++i) {
    int idx = (i*512 + t)*4;
    f32x4 s = {};
#pragma unroll
    for (int kc = 0; kc < 8; ++kc)
      s += *(const f32x4*)&Apart[((size_t)(kc*16 + h))*4096 + idx];
    int r = idx >> 6, c = idx & 63;
    *(f32x4*)&Af[r][c] = s;
    union { int2 v; short sh[4]; } pk;
#pragma unroll
    for (int j = 0; j < 4; ++j) pk.sh[j] = f2b(s[j]);
    *(int2*)&Afb[r][c] = pk.v;
  }
  __syncthreads();
  for (int layer = 0; layer < 2; ++layer) {
    const short* w1l = w1T + layer*65536;
    const short* w2l = w2T + layer*65536;
    f32x4 acc2[4][4] = {};
    for (int kc = 0; kc < 2; ++kc) {
      // d1: this wave computes cols [kc*512 + w*64, +64) of hd
      int c0g = kc*512 + w*64;
      f32x4 acc1[4][4] = {};
#pragma unroll
      for (int kk = 0; kk < 2; ++kk) {
        bf16x8 aA[4], bW[4];
#pragma unroll
        for (int mf = 0; mf < 4; ++mf)
          aA[mf] = *(const bf16x8*)&Afb[mf*16 + rA][kk*32 + kg*8];
#pragma unroll
        for (int nf = 0; nf < 4; ++nf)
          bW[nf] = *(const bf16x8*)&w1l[(size_t)(c0g + nf*16 + rA)*64 + kk*32 + kg*8];
#pragma unroll
        for (int mf = 0; mf < 4; ++mf)
#pragma unroll
          for (int nf = 0; nf < 4; ++nf)
            acc1[mf][nf] = MFMA16(aA[mf], bW[nf], acc1[mf][nf]);
      }
      __syncthreads();   // prior d2 reads of hd done before overwrite
#pragma unroll
      for (int nf = 0; nf < 4; ++nf) {
        int col = w*64 + nf*16 + rA;
        float bb1 = b1[layer*1024 + kc*512 + col];
#pragma unroll
        for (int mf = 0; mf < 4; ++mf)
#pragma unroll
          for (int rr = 0; rr < 4; ++rr) {
            int r = mf*16 + kg*4 + rr;
            hdP[r*520 + col] = f2b(fmaxf(acc1[mf][nf][rr] + bb1, 0.f));
          }
      }
      __syncthreads();   // hd ready
      // d2: this wave's K-slice = hd cols [w*64, +64)
#pragma unroll
      for (int kk = 0; kk < 2; ++kk) {
        bf16x8 a2[4], bw2[4];
#pragma unroll
        for (int mf = 0; mf < 4; ++mf)
          a2[mf] = *(const bf16x8*)&hdP[(mf*16 + rA)*520 + w*64 + kk*32 + kg*8];
#pragma unroll
        for (int nf = 0; nf < 4; ++nf)
          bw2[nf] = *(const bf16x8*)&w2l[(size_t)(nf*16 + rA)*1024 + kc*512 + w*64 + kk*32 + kg*8];
#pragma unroll
        for (int mf = 0; mf < 4; ++mf)
#pragma unroll
          for (int nf = 0; nf < 4; ++nf)
            acc2[mf][nf] = MFMA16(a2[mf], bw2[nf], acc2[mf][nf]);
      }
    }
    __syncthreads();     // d2 hd reads done; reuse hdP for partials
    float* P = (float*)hdP;
    if (w >= 4) {
      int slot = w - 4;
#pragma unroll
      for (int mf = 0; mf < 4; ++mf)
#pragma unroll
        for (int nf = 0; nf < 4; ++nf)
#pragma unroll
          for (int rr = 0; rr < 4; ++rr)
            P[slot*4160 + (mf*16 + kg*4 + rr)*65 + nf*16 + rA] = acc2[mf][nf][rr];
    }
    __syncthreads();
    if (w < 4) {
#pragma unroll
      for (int mf = 0; mf < 4; ++mf)
#pragma unroll
        for (int nf = 0; nf < 4; ++nf)
#pragma unroll
          for (int rr = 0; rr < 4; ++rr)
            P[w*4160 + (mf*16 + kg*4 + rr)*65 + nf*16 + rA] += acc2[mf][nf][rr];
    }
    __syncthreads();
    // sum 4 partials + b2 + residual, LN per row
    int r = t >> 3, j0 = (t & 7)*8;
    float x[8], s1 = 0.f, s2 = 0.f;
#pragma unroll
    for (int j = 0; j < 8; ++j) {
      int c = j0 + j;
      float xx = P[r*65 + c] + P[4160 + r*65 + c] + P[8320 + r*65 + c] + P[12480 + r*65 + c]
               + b2[layer*64 + c] + Af[r][c];
      x[j] = xx; s1 += xx; s2 += xx*xx;
    }
    s1 += __shfl_xor(s1, 1); s1 += __shfl_xor(s1, 2); s1 += __shfl_xor(s1, 4);
    s2 += __shfl_xor(s2, 1); s2 += __shfl_xor(s2, 2); s2 += __shfl_xor(s2, 4);
    float mean = s1 * (1.f/64.f);
    float var  = s2 * (1.f/64.f) - mean*mean;
    float rstd = rsqrtf(var + 1e-6f);
#pragma unroll
    for (int j = 0; j < 8; ++j) {
      int c = j0 + j;
      float nx = (x[j] - mean)*rstd*gl[layer*64 + c] + bel[layer*64 + c];
      Af[r][c] = nx;
      Afb[r][c] = f2b(nx);
      if (layer == 1) outB[OFF_A + (size_t)h*4096 + r*64 + c] = nx;
    }
    __syncthreads();
  }
  // avAp
  {
    int e = t & 63, dg = t >> 6;
    float pe = pwv[e], p = 0.f;
#pragma unroll
    for (int j = 0; j < 8; ++j) {
      int d = dg*8 + j;
      p += av[d] * powf(fabsf(Af[d][e]) + 1e-9f, pe);
    }
    red[dg][e] = p;
  }
  __syncthreads();
  if (t < 64) {
    float tot = 0.f;
#pragma unroll
    for (int g = 0; g < 8; ++g) tot += red[g][t];
    avApW[h*64 + t] = tot;
    outB[OFF_AVAP + h*64 + t] = tot;
  }
  if (h == 0) {
    if (t < 64) outB[OFF_PW + t] = pwv[t];
    if (t == 0) outB[OFF_BA] = bav[0];
  }
}

// ---------------- pass1: E/Ep (two-round LDS staging, 32KB) + softmax partials ----------------
__global__ __launch_bounds__(256) void k_pass1(
    const short* __restrict__ qh, const short* __restrict__ kh,
    const float* __restrict__ avAp, const float* __restrict__ mask,
    const float* __restrict__ bap, float* __restrict__ outB,
    float2* __restrict__ part) {
  __shared__ float Et[64*128];    // 32KB; phase A holds Qs/Ks bf16, phase B holds half E tile
  __shared__ float avl[64];
  short* Qs = (short*)Et;          // [0, 16KB)
  short* Ks = ((short*)Et) + 8192; // [16KB, 32KB)
  int tt = blockIdx.x, st = blockIdx.y, h = blockIdx.z;
  int s0 = st*128, t0 = tt*128;
  int t = threadIdx.x, lane = t & 63;
  int wr = t >> 7, wc = (t >> 6) & 1;
  int rA = lane & 15, kg = lane >> 4;
  if (t < 16) *(f32x4*)&avl[t*4] = *(const f32x4*)&avAp[h*64 + t*4];
  __syncthreads();
#pragma unroll
  for (int i = 0; i < 4; ++i) {
    int cid = i*256 + t, row = cid >> 3, c = cid & 7, cs = c ^ (row & 7);
    union { int4 v; short s[8]; } qa, qo;
    qa.v = *(const int4*)&qh[((size_t)h*S_ + s0 + row)*DEP_ + c*8];
#pragma unroll
    for (int j = 0; j < 8; ++j) qo.s[j] = f2b(b2f(qa.s[j]) * avl[c*8 + j]);
    *(int4*)&Qs[row*64 + cs*8] = qo.v;
    *(int4*)&Ks[row*64 + cs*8] = *(const int4*)&kh[((size_t)h*S_ + t0 + row)*DEP_ + c*8];
  }
  __syncthreads();
  f32x4 acc[4][4] = {};
#pragma unroll
  for (int kk = 0; kk < 2; ++kk) {
    bf16x8 a[4], b[4];
#pragma unroll
    for (int m = 0; m < 4; ++m) {
      int row = wr*64 + m*16 + rA, c = (kk*4 + kg) ^ (row & 7);
      a[m] = *(const bf16x8*)&Qs[row*64 + c*8];
    }
#pragma unroll
    for (int n = 0; n < 4; ++n) {
      int row = wc*64 + n*16 + rA, c = (kk*4 + kg) ^ (row & 7);
      b[n] = *(const bf16x8*)&Ks[row*64 + c*8];
    }
#pragma unroll
    for (int m = 0; m < 4; ++m)
#pragma unroll
      for (int n = 0; n < 4; ++n)
        acc[m][n] = MFMA16(b[n], a[m], acc[m][n]);   // swapped: lane holds 4 consecutive t
  }
  // stats from fragments
  float bav = bap[0];
  f32x4 mkf[4];
#pragma unroll
  for (int n = 0; n < 4; ++n) {
    f32x4 mm = *(const f32x4*)&mask[t0 + wc*64 + n*16 + kg*4];
#pragma unroll
    for (int j = 0; j < 4; ++j) mkf[n][j] = mm[j] * (-1e9f);
  }
#pragma unroll
  for (int m = 0; m < 4; ++m) {
    int row = s0 + wr*64 + m*16 + rA;
    float mx = -3.4e38f;
    f32x4 ep4[4];
#pragma unroll
    for (int n = 0; n < 4; ++n) {
      f32x4 e = acc[m][n];
      f32x4 ep;
#pragma unroll
      for (int j = 0; j < 4; ++j) {
        float ee = e[j];
        ep[j] = (ee > 0.f ? ee : 0.2f*ee) + bav + mkf[n][j];
        mx = fmaxf(mx, ep[j]);
      }
      ep4[n] = ep;
    }
    mx = fmaxf(mx, __shfl_xor(mx, 16));
    mx = fmaxf(mx, __shfl_xor(mx, 32));
    float sm = 0.f;
#pragma unroll
    for (int n = 0; n < 4; ++n)
#pragma unroll
      for (int j = 0; j < 4; ++j) sm += expf(ep4[n][j] - mx);
    sm += __shfl_xor(sm, 16);
    sm += __shfl_xor(sm, 32);
    if (kg == 0)
      part[((size_t)(h*S_ + row)*16 + tt)*2 + wc] = make_float2(mx, sm);
  }
  // two-round coalesced E/Ep store via 32KB LDS half-tiles
  float* Eo  = outB + OFF_E;
  float* Epo = outB + OFF_EP;
  int colu = t & 31, rbase = t >> 5;
  f32x4 mm4 = *(const f32x4*)&mask[t0 + colu*4];
  f32x4 mk4;
#pragma unroll
  for (int j = 0; j < 4; ++j) mk4[j] = mm4[j] * (-1e9f);
  __syncthreads();   // Qs/Ks reads done
#pragma unroll
  for (int half = 0; half < 2; ++half) {
    if (wr == half) {
#pragma unroll
      for (int m = 0; m < 4; ++m)
#pragma unroll
        for (int n = 0; n < 4; ++n) {
          int row_l = m*16 + rA;
          int unit = wc*16 + n*4 + kg;
          *(f32x4*)&Et[row_l*128 + ((unit ^ (row_l & 7)))*4] = acc[m][n];
        }
    }
    __syncthreads();
#pragma unroll
    for (int r = 0; r < 8; ++r) {
      int row_l = r*8 + rbase;
      f32x4 e = *(const f32x4*)&Et[row_l*128 + ((colu ^ (row_l & 7)))*4];
      size_t gb = ((size_t)h*S_ + s0 + half*64 + row_l)*S_ + t0 + colu*4;
      st4(&Eo[gb], e);
      f32x4 ep;
#pragma unroll
      for (int j = 0; j < 4; ++j)
        ep[j] = (e[j] > 0.f ? e[j] : 0.2f*e[j]) + bav + mk4[j];
      st4(&Epo[gb], ep);
    }
    __syncthreads();
  }
}

// ---------------- pass2: fin-reduce prologue + attv (full-line) + PV partial ----------------
__global__ __launch_bounds__(256) void k_pass2(
    const short* __restrict__ qh, const short* __restrict__ kh,
    const short* __restrict__ vhT, const float* __restrict__ avAp,
    const float* __restrict__ mask, const float* __restrict__ bap,
    const float2* __restrict__ part, float* __restrict__ attv,
    short* __restrict__ Hnp0, short* __restrict__ Hnp1) {
  __shared__ short Qs[128*64];
  __shared__ short KP[128*128];   // union: kh tile (stride 64) / P tile (stride 128, swz)
  __shared__ short Vs[64*128];
  __shared__ float avl[64];
  __shared__ float2 finS[128];
  int st = blockIdx.x, tc = blockIdx.y, h = blockIdx.z;
  int s0 = st * 128;
  int t = threadIdx.x, lane = t & 63;
  int wr = t >> 7, wc = (t >> 6) & 1;
  int rA = lane & 15, kg = lane >> 4;
  if (t < 16) *(f32x4*)&avl[t*4] = *(const f32x4*)&avAp[h*64 + t*4];
  if (t < 128) {
    const float2* pp = part + (size_t)(h*S_ + s0 + t) * 32;
    float M = -3.4e38f;
    for (int i = 0; i < 32; ++i) M = fmaxf(M, pp[i].x);
    float L = 0.f;
    for (int i = 0; i < 32; ++i) L += pp[i].y * expf(pp[i].x - M);
    finS[t] = make_float2(M, 1.f / L);
  }
  __syncthreads();
#pragma unroll
  for (int i = 0; i < 4; ++i) {
    int cid = i*256 + t, row = cid >> 3, c = cid & 7, cs = c ^ (row & 7);
    union { int4 v; short s[8]; } qa, qo;
    qa.v = *(const int4*)&qh[((size_t)h*S_ + s0 + row)*DEP_ + c*8];
#pragma unroll
    for (int j = 0; j < 8; ++j) qo.s[j] = f2b(b2f(qa.s[j]) * avl[c*8 + j]);
    *(int4*)&Qs[row*64 + cs*8] = qo.v;
  }
  float Ms[4], Li[4];
#pragma unroll
  for (int m = 0; m < 4; ++m) {
    float2 f = finS[wr*64 + m*16 + rA];
    Ms[m] = f.x; Li[m] = f.y;
  }
  float bav = bap[0];
  __syncthreads();
  bf16x8 aq[4][2];
#pragma unroll
  for (int m = 0; m < 4; ++m)
#pragma unroll
    for (int kk = 0; kk < 2; ++kk) {
      int row = wr*64 + m*16 + rA, c = (kk*4 + kg) ^ (row & 7);
      aq[m][kk] = *(const bf16x8*)&Qs[row*64 + c*8];
    }
  f32x4 acc2[4][2] = {};
  for (int tt = tc*8; tt < tc*8 + 8; ++tt) {
    int t0 = tt * 128;
    __syncthreads();    // prev iteration's P/V/attv reads done
#pragma unroll
    for (int i = 0; i < 4; ++i) {
      int cid = i*256 + t, row = cid >> 3, c = cid & 7, cs = c ^ (row & 7);
      *(int4*)&KP[row*64 + cs*8] = *(const int4*)&kh[((size_t)h*S_ + t0 + row)*DEP_ + c*8];
    }
#pragma unroll
    for (int i = 0; i < 4; ++i) {
      int cid = i*256 + t, row = cid >> 4, c = cid & 15, cs = c ^ (row & 7);
      *(int4*)&Vs[row*128 + cs*8] = *(const int4*)&vhT[((size_t)h*DEP_ + row)*S_ + t0 + c*8];
    }
    __syncthreads();
    f32x4 accE[4][4] = {};
#pragma unroll
    for (int kk = 0; kk < 2; ++kk) {
      bf16x8 b[4];
#pragma unroll
      for (int n = 0; n < 4; ++n) {
        int row = wc*64 + n*16 + rA, c = (kk*4 + kg) ^ (row & 7);
        b[n] = *(const bf16x8*)&KP[row*64 + c*8];
      }
#pragma unroll
      for (int m = 0; m < 4; ++m)
#pragma unroll
        for (int n = 0; n < 4; ++n)
          accE[m][n] = MFMA16(b[n], aq[m][kk], accE[m][n]);   // swapped
    }
    f32x4 mkf[4];
#pragma unroll
    for (int n = 0; n < 4; ++n) {
      f32x4 mm = *(const f32x4*)&mask[t0 + wc*64 + n*16 + kg*4];
#pragma unroll
      for (int j = 0; j < 4; ++j) mkf[n][j] = mm[j] * (-1e9f);
    }
#pragma unroll
    for (int m = 0; m < 4; ++m)
#pragma unroll
      for (int n = 0; n < 4; ++n) {
        f32x4 e = accE[m][n], p;
#pragma unroll
        for (int j = 0; j < 4; ++j) {
          float ep = (e[j] > 0.f ? e[j] : 0.2f*e[j]) + bav + mkf[n][j];
          p[j] = expf(ep - Ms[m]) * Li[m];
        }
        accE[m][n] = p;
      }
    __syncthreads();    // all KP(kh) fragment reads done before P overwrites
#pragma unroll
    for (int m = 0; m < 4; ++m) {
      int srow = wr*64 + m*16 + rA;
#pragma unroll
      for (int n = 0; n < 4; ++n) {
        int tcol = wc*64 + n*16 + kg*4;
        union { int2 v; short s[4]; } pk;
#pragma unroll
        for (int j = 0; j < 4; ++j) pk.s[j] = f2b(accE[m][n][j]);
        *(int2*)((char*)KP + srow*256 + ((tcol*2) ^ ((srow & 7) << 4))) = pk.v;
      }
    }
    __syncthreads();
#pragma unroll
    for (int kkp = 0; kkp < 4; ++kkp) {
      bf16x8 ap[4], bv[2];
#pragma unroll
      for (int m = 0; m < 4; ++m) {
        int row = wr*64 + m*16 + rA;
        ap[m] = *(const bf16x8*)((const char*)KP + row*256 + ((kkp*64 + kg*16) ^ ((row & 7) << 4)));
      }
#pragma unroll
      for (int n = 0; n < 2; ++n) {
        int dd = wc*32 + n*16 + rA, c = (kkp*4 + kg) ^ (dd & 7);
        bv[n] = *(const bf16x8*)&Vs[dd*128 + c*8];
      }
#pragma unroll
      for (int m = 0; m < 4; ++m)
#pragma unroll
        for (int n = 0; n < 2; ++n)
          acc2[m][n] = MFMA16(ap[m], bv[n], acc2[m][n]);
    }
    // attv store: full-line per instruction (2 rows x 512B per wave instr)
#pragma unroll
    for (int it = 0; it < 16; ++it) {
      int row = it*8 + (t >> 5);
      int u8 = t & 31;
      union { int2 v; short s[4]; } pv;
      pv.v = *(const int2*)((const char*)KP + row*256 + ((u8*8) ^ ((row & 7) << 4)));
      f32x4 o;
#pragma unroll
      for (int j = 0; j < 4; ++j) o[j] = b2f(pv.s[j]);
      st4(&attv[((size_t)h*S_ + s0 + row)*S_ + t0 + u8*4], o);
    }
  }
  short* Hp = tc ? Hnp1 : Hnp0;
#pragma unroll
  for (int m = 0; m < 4; ++m)
#pragma unroll
    for (int n = 0; n < 2; ++n)
#pragma unroll
      for (int rr = 0; rr < 4; ++rr) {
        int row = s0 + wr*64 + m*16 + kg*4 + rr;
        int dd = wc*32 + n*16 + rA;
        Hp[(size_t)row*D_ + h*DEP_ + dd] = f2b(acc2[m][n][rr]);
      }
}

extern "C" void kernel_launch(void* const* d_in, const int* in_sizes, int n_in,
                              void* d_out, int out_size, void* d_ws, size_t ws_size,
                              hipStream_t stream) {
  (void)in_sizes; (void)n_in; (void)out_size; (void)ws_size;
  const float* q    = (const float*)d_in[0];
  const float* k    = (const float*)d_in[1];
  const float* v    = (const float*)d_in[2];
  const float* mask = (const float*)d_in[3];
  const float* wq_w = (const float*)d_in[4];
  const float* wq_b = (const float*)d_in[5];
  const float* wk_w = (const float*)d_in[6];
  const float* wk_b = (const float*)d_in[7];
  const float* wv_w = (const float*)d_in[8];
  const float* wv_b = (const float*)d_in[9];
  const float* wo_w = (const float*)d_in[10];
  const float* wo_b = (const float*)d_in[11];
  const float* rl_w1 = (const float*)d_in[12];
  const float* rl_b1 = (const float*)d_in[13];
  const float* rl_w2 = (const float*)d_in[14];
  const float* rl_b2 = (const float*)d_in[15];
  const float* rl_g  = (const float*)d_in[16];
  const float* rl_be = (const float*)d_in[17];
  const float* pw    = (const float*)d_in[18];
  const float* avec  = (const float*)d_in[19];
  const float* ba    = (const float*)d_in[20];
  float* outf = (float*)d_out;

  // Workspace map (lifetime-based reuse, peak <= 32.5 MB)
  char* w = (char*)d_ws;
  short* xbf  = (short*)(w);                              // 0..12M  (dead after QKV gemm)
  short* wT   = (short*)(w + (12u << 20));                // 12..20M; woT @18M lives to end
  short* qh   = (short*)(w + (20u << 20));                // 20..24M (live to pass2)
  short* kh   = (short*)(w + (24u << 20));                // 24..28M (live to pass2)
  short* vh   = (short*)(w + (28u << 20));                // 28..32M (dead after transpose)
  short* qhT  = (short*)(w);                              // 0..4M   (dead after metric_p)
  short* vhT  = (short*)(w + (4u << 20));                 // 4..8M   (live to pass2)
  float* Apart = (float*)(w + (12u << 20));               // 2MB over wqT (dead after qkv)
  float2* part = (float2*)(w + (8u << 20));               // 8..16M  (written pass1, read pass2)
  float* avApW = (float*)(w + (16u << 20) + (512u << 10));// 4KB over wvT weight (dead)
  short* w1T  = (short*)(w + (32u << 20));                // 256KB (live until k_res)
  short* w2T  = (short*)(w + (32u << 20) + (256u << 10)); // 256KB
  short* Hnp0 = (short*)(w);                              // 0..4M  (over qhT, dead)
  short* Hnp1 = (short*)(w + (28u << 20));                // 28..32M (over vh, dead)

  k_cvt_all<<<dim3(7232), 256, 0, stream>>>(q, k, v, wq_w, wk_w, wv_w, wo_w,
                                            rl_w1, rl_w2, xbf, wT, w1T, w2T);
  k_gemm<<<dim3(16, 8, 3), 256, 0, stream>>>(xbf, nullptr, wT, wq_b, wk_b, wv_b,
                                             qh, nullptr, 0);
  k_transpose<<<dim3(32, 16, 2), 256, 0, stream>>>(qh, vh, qhT, vhT);
  k_metric_p<<<dim3(8, 16), 256, 0, stream>>>(qhT, Apart);
  k_res<<<dim3(16), 512, 0, stream>>>(Apart, w1T, rl_b1, w2T, rl_b2, rl_g, rl_be,
                                      pw, avec, ba, avApW, outf);
  k_pass1<<<dim3(16, 16, 16), 256, 0, stream>>>(qh, kh, avApW, mask, ba, outf, part);
  k_pass2<<<dim3(16, 2, 16), 256, 0, stream>>>(qh, kh, vhT, avApW, mask, ba, part,
                                               outf + OFF_ATT, Hnp0, Hnp1);
  k_gemm<<<dim3(16, 8, 1), 256, 0, stream>>>(Hnp0, Hnp1, wT + 3u*D_*D_,
                                             wo_b, wo_b, wo_b, nullptr, outf, 2);
}

// Round 8
// 475.046 us; speedup vs baseline: 1.1580x; 1.1580x over previous
//
#include <hip/hip_runtime.h>
#include <stdint.h>

#define S_ 2048
#define D_ 1024
#define H_ 16
#define DEP_ 64

typedef float f32x4 __attribute__((ext_vector_type(4)));
typedef __bf16 bf16x8 __attribute__((ext_vector_type(8)));

#define MFMA16(a,b,c) __builtin_amdgcn_mfma_f32_16x16x32_bf16((a),(b),(c),0,0,0)

// Output offsets (floats): (out, E, A, pw, attv, ba, avAp, Ep)
static constexpr size_t OFF_E    = 2097152ull;
static constexpr size_t OFF_A    = 69206016ull;
static constexpr size_t OFF_PW   = 69271552ull;
static constexpr size_t OFF_ATT  = 69271616ull;
static constexpr size_t OFF_BA   = 136380480ull;
static constexpr size_t OFF_AVAP = 136380481ull;
static constexpr size_t OFF_EP   = 136381505ull;

__device__ __forceinline__ short f2b(float f) {
  union { float f; uint32_t u; } c; c.f = f;
  uint32_t u = c.u;
  uint32_t r = (u + 0x7fffu + ((u >> 16) & 1u)) >> 16;
  return (short)(r & 0xffffu);
}
__device__ __forceinline__ float b2f(short s) {
  union { uint32_t u; float f; } c; c.u = ((uint32_t)(uint16_t)s) << 16;
  return c.f;
}
__device__ __forceinline__ void st_nt(float* p, f32x4 v) {
  __builtin_nontemporal_store(v, (f32x4*)p);
}

// ---------------- fused converts: inputs, proj weights, res weights ----------------
__global__ void k_cvt_all(const float* __restrict__ q, const float* __restrict__ k,
                          const float* __restrict__ v, const float* __restrict__ wq,
                          const float* __restrict__ wk, const float* __restrict__ wv,
                          const float* __restrict__ wo, const float* __restrict__ w1,
                          const float* __restrict__ w2, short* __restrict__ xbf,
                          short* __restrict__ wT, short* __restrict__ w1T,
                          short* __restrict__ w2T) {
  __shared__ float tile[64][65];
  int bid = blockIdx.x, t = threadIdx.x;
  if (bid < 6144) {
    int z = bid >> 11, bx = bid & 2047;
    const float* src = (z == 0) ? q : (z == 1) ? k : v;
    short* d = xbf + (size_t)z * (S_*D_);
    int i = (bx*256 + t)*4;
    float4 f = *(const float4*)(src + i);
    short4 o;
    o.x = f2b(f.x); o.y = f2b(f.y); o.z = f2b(f.z); o.w = f2b(f.w);
    *(short4*)(d + i) = o;
  } else if (bid < 7168) {
    int u = bid - 6144, z = u >> 8, tl = u & 255;
    int k0 = (tl >> 4)*64, n0 = (tl & 15)*64;
    const float* W = (z == 0) ? wq : (z == 1) ? wk : (z == 2) ? wv : wo;
    short* d = wT + (size_t)z * (D_*D_);
    for (int i = 0; i < 16; ++i) {
      int e = i*256 + t, r = e >> 6, c = e & 63;
      tile[r][c] = W[(size_t)(k0+r)*D_ + n0 + c];
    }
    __syncthreads();
    for (int i = 0; i < 16; ++i) {
      int e = i*256 + t, r = e >> 6, c = e & 63;
      d[(size_t)(n0+r)*D_ + k0 + c] = f2b(tile[c][r]);
    }
  } else {
    int u = bid - 7168, z = u >> 4, bx = u & 15;
    int l = z >> 1, which = z & 1;
    if (which == 0) {
      const float* src = w1 + (size_t)l*65536;
      short* d = w1T + (size_t)l*65536;
      int n0 = bx*64;
      for (int i = 0; i < 16; ++i) {
        int e = i*256 + t, r = e >> 6, c = e & 63;
        tile[r][c] = src[(size_t)r*1024 + n0 + c];
      }
      __syncthreads();
      for (int i = 0; i < 16; ++i) {
        int e = i*256 + t, r = e >> 6, c = e & 63;
        d[(size_t)(n0+r)*64 + c] = f2b(tile[c][r]);
      }
    } else {
      const float* src = w2 + (size_t)l*65536;
      short* d = w2T + (size_t)l*65536;
      int k0 = bx*64;
      for (int i = 0; i < 16; ++i) {
        int e = i*256 + t, r = e >> 6, c = e & 63;
        tile[r][c] = src[(size_t)(k0+r)*64 + c];
      }
      __syncthreads();
      for (int i = 0; i < 16; ++i) {
        int e = i*256 + t, r = e >> 6, c = e & 63;
        d[(size_t)r*1024 + k0 + c] = f2b(tile[c][r]);
      }
    }
  }
}

// ---------------- 128x128 bf16 GEMM: C = X @ WT^T + bias ----------------
// mode 0: write bf16 head-major (LDS-staged); mode 2: X = X + X2, write f32 outf (staged)
__global__ __launch_bounds__(256) void k_gemm(
    const short* __restrict__ Xall, const short* __restrict__ X2,
    const short* __restrict__ WTall,
    const float* __restrict__ b0, const float* __restrict__ b1v,
    const float* __restrict__ b2v, short* __restrict__ dstall,
    float* __restrict__ outf, int mode) {
  __shared__ __align__(16) short SS[2*128*72];   // As/Bs in K-loop; C staging after
  short* As = SS;
  short* Bs = SS + 128*72;
  int z = blockIdx.z;
  const short* X  = Xall + (size_t)z * (S_*D_);
  const short* WT = WTall + (size_t)z * (D_*D_);
  int m0 = blockIdx.x * 128, n0 = blockIdx.y * 128;
  int t = threadIdx.x, lane = t & 63;
  int wr = t >> 7, wc = (t >> 6) & 1;
  int rA = lane & 15, kg = lane >> 4;
  f32x4 acc[4][4] = {};
  for (int kt = 0; kt < 16; ++kt) {
#pragma unroll
    for (int i = 0; i < 4; ++i) {
      int cid = i*256 + t, row = cid >> 3, c = cid & 7;
      size_t xi = (size_t)(m0+row)*D_ + kt*64 + c*8;
      if (mode == 2) {
        union { int4 v; short s[8]; } a1, a2, o;
        a1.v = *(const int4*)&X[xi];
        a2.v = *(const int4*)&X2[xi];
#pragma unroll
        for (int j = 0; j < 8; ++j) o.s[j] = f2b(b2f(a1.s[j]) + b2f(a2.s[j]));
        *(int4*)&As[row*72 + c*8] = o.v;
      } else {
        *(int4*)&As[row*72 + c*8] = *(const int4*)&X[xi];
      }
      *(int4*)&Bs[row*72 + c*8] = *(const int4*)&WT[(size_t)(n0+row)*D_ + kt*64 + c*8];
    }
    __syncthreads();
#pragma unroll
    for (int kk = 0; kk < 2; ++kk) {
      bf16x8 a[4], b[4];
#pragma unroll
      for (int m = 0; m < 4; ++m)
        a[m] = *(const bf16x8*)&As[(wr*64 + m*16 + rA)*72 + kk*32 + kg*8];
#pragma unroll
      for (int n = 0; n < 4; ++n)
        b[n] = *(const bf16x8*)&Bs[(wc*64 + n*16 + rA)*72 + kk*32 + kg*8];
#pragma unroll
      for (int m = 0; m < 4; ++m)
#pragma unroll
        for (int n = 0; n < 4; ++n)
          acc[m][n] = MFMA16(a[m], b[n], acc[m][n]);
    }
    __syncthreads();
  }
  const float* bias = (mode != 0) ? b0 : (z == 0 ? b0 : (z == 1 ? b1v : b2v));
  if (mode == 0) {
    // stage bf16 tile [128][136] then coalesced head-major stores
    short* Ct = SS;
#pragma unroll
    for (int m = 0; m < 4; ++m)
#pragma unroll
      for (int n = 0; n < 4; ++n) {
        int col = wc*64 + n*16 + rA;
        float bb = bias[n0 + col];
#pragma unroll
        for (int rr = 0; rr < 4; ++rr) {
          int row = wr*64 + m*16 + kg*4 + rr;
          Ct[row*136 + col] = f2b(acc[m][n][rr] + bb);
        }
      }
    __syncthreads();
#pragma unroll
    for (int p = 0; p < 8; ++p) {
      int row = p*16 + (t >> 4), unit = t & 15;
      int4 vv = *(const int4*)&Ct[row*136 + unit*8];
      int gcol = n0 + unit*8;
      int head = gcol >> 6, dd = gcol & 63;
      *(int4*)&dstall[(size_t)z*(S_*D_) + ((size_t)head*S_ + m0 + row)*DEP_ + dd] = vv;
    }
  } else {
    // stage f32 in two 64-row halves [64][132], coalesced nt stores
    float* Ct = (float*)SS;
#pragma unroll
    for (int half = 0; half < 2; ++half) {
      if (wr == half) {
#pragma unroll
        for (int m = 0; m < 4; ++m)
#pragma unroll
          for (int n = 0; n < 4; ++n) {
            int col = wc*64 + n*16 + rA;
            float bb = bias[n0 + col];
#pragma unroll
            for (int rr = 0; rr < 4; ++rr)
              Ct[(m*16 + kg*4 + rr)*132 + col] = acc[m][n][rr] + bb;
          }
      }
      __syncthreads();
#pragma unroll
      for (int p = 0; p < 8; ++p) {
        int row_l = p*8 + (t >> 5), unit = t & 31;
        f32x4 vv = *(const f32x4*)&Ct[row_l*132 + unit*4];
        st_nt(&outf[(size_t)(m0 + half*64 + row_l)*D_ + n0 + unit*4], vv);
      }
      __syncthreads();
    }
  }
}

// ---------------- bf16 transpose [h][S][64] -> [h][64][S] ----------------
__global__ void k_transpose(const short* __restrict__ qh, const short* __restrict__ vh,
                            short* __restrict__ qhT, short* __restrict__ vhT) {
  __shared__ short tile[64][68];
  const short* src = blockIdx.z ? vh : qh;
  short* dst = blockIdx.z ? vhT : qhT;
  int h = blockIdx.y, s0 = blockIdx.x * 64, t = threadIdx.x;
  for (int i = 0; i < 16; ++i) {
    int e = i*256 + t, r = e >> 6, c = e & 63;
    tile[r][c] = src[((size_t)h*S_ + s0 + r)*DEP_ + c];
  }
  __syncthreads();
  for (int i = 0; i < 16; ++i) {
    int e = i*256 + t, r = e >> 6, c = e & 63;
    dst[((size_t)h*DEP_ + r)*S_ + s0 + c] = tile[c][r];
  }
}

// ---------------- metric partial ----------------
__global__ __launch_bounds__(256) void k_metric_p(const short* __restrict__ qhT,
                                                  float* __restrict__ Apart) {
  __shared__ short qt[64*72];
  int kc = blockIdx.x, h = blockIdx.y, t = threadIdx.x, lane = t & 63;
  int wr = t >> 7, wc = (t >> 6) & 1;
  int rA = lane & 15, kg = lane >> 4;
  f32x4 acc[2][2] = {};
  for (int kt = 0; kt < 4; ++kt) {
#pragma unroll
    for (int i = 0; i < 2; ++i) {
      int cid = i*256 + t, row = cid >> 3, c = cid & 7;
      *(int4*)&qt[row*72 + c*8] =
        *(const int4*)&qhT[((size_t)h*DEP_ + row)*S_ + kc*256 + kt*64 + c*8];
    }
    __syncthreads();
#pragma unroll
    for (int kk = 0; kk < 2; ++kk) {
      bf16x8 a[2], b[2];
#pragma unroll
      for (int m = 0; m < 2; ++m)
        a[m] = *(const bf16x8*)&qt[(wr*32 + m*16 + rA)*72 + kk*32 + kg*8];
#pragma unroll
      for (int n = 0; n < 2; ++n)
        b[n] = *(const bf16x8*)&qt[(wc*32 + n*16 + rA)*72 + kk*32 + kg*8];
#pragma unroll
      for (int m = 0; m < 2; ++m)
#pragma unroll
        for (int n = 0; n < 2; ++n)
          acc[m][n] = MFMA16(a[m], b[n], acc[m][n]);
    }
    __syncthreads();
  }
#pragma unroll
  for (int m = 0; m < 2; ++m)
#pragma unroll
    for (int n = 0; n < 2; ++n)
#pragma unroll
      for (int rr = 0; rr < 4; ++rr) {
        int row = wr*32 + m*16 + kg*4 + rr, col = wc*32 + n*16 + rA;
        Apart[((size_t)(kc*16 + h))*4096 + row*64 + col] = acc[m][n][rr];
      }
}

// ---------------- fused res stack: metric reduce + 2x(d1+d2+LN) + avAp ----------------
__global__ __launch_bounds__(512) void k_res(
    const float* __restrict__ Apart, const short* __restrict__ w1T,
    const float* __restrict__ b1, const short* __restrict__ w2T,
    const float* __restrict__ b2, const float* __restrict__ gl,
    const float* __restrict__ bel, const float* __restrict__ pwv,
    const float* __restrict__ av, const float* __restrict__ bav,
    float* __restrict__ avApW, float* __restrict__ outB) {
  __shared__ float Af[64][68];     // current activation (residual source)
  __shared__ short Afb[64][72];    // bf16 mirror for MFMA A-op
  __shared__ short hdP[64*520];    // hd bf16 [64][520] / d2 partials f32 [4][64][65]
  __shared__ float red[8][64];
  int h = blockIdx.x, t = threadIdx.x;
  int lane = t & 63, w = t >> 6;
  int rA = lane & 15, kg = lane >> 4;
#pragma unroll
  for (int i = 0; i < 2; ++i) {
    int idx = (i*512 + t)*4;
    f32x4 s = {};
#pragma unroll
    for (int kc = 0; kc < 8; ++kc)
      s += *(const f32x4*)&Apart[((size_t)(kc*16 + h))*4096 + idx];
    int r = idx >> 6, c = idx & 63;
    *(f32x4*)&Af[r][c] = s;
    union { int2 v; short sh[4]; } pk;
#pragma unroll
    for (int j = 0; j < 4; ++j) pk.sh[j] = f2b(s[j]);
    *(int2*)&Afb[r][c] = pk.v;
  }
  __syncthreads();
  for (int layer = 0; layer < 2; ++layer) {
    const short* w1l = w1T + layer*65536;
    const short* w2l = w2T + layer*65536;
    f32x4 acc2[4][4] = {};
    for (int kc = 0; kc < 2; ++kc) {
      int c0g = kc*512 + w*64;
      f32x4 acc1[4][4] = {};
#pragma unroll
      for (int kk = 0; kk < 2; ++kk) {
        bf16x8 aA[4], bW[4];
#pragma unroll
        for (int mf = 0; mf < 4; ++mf)
          aA[mf] = *(const bf16x8*)&Afb[mf*16 + rA][kk*32 + kg*8];
#pragma unroll
        for (int nf = 0; nf < 4; ++nf)
          bW[nf] = *(const bf16x8*)&w1l[(size_t)(c0g + nf*16 + rA)*64 + kk*32 + kg*8];
#pragma unroll
        for (int mf = 0; mf < 4; ++mf)
#pragma unroll
          for (int nf = 0; nf < 4; ++nf)
            acc1[mf][nf] = MFMA16(aA[mf], bW[nf], acc1[mf][nf]);
      }
      __syncthreads();
#pragma unroll
      for (int nf = 0; nf < 4; ++nf) {
        int col = w*64 + nf*16 + rA;
        float bb1 = b1[layer*1024 + kc*512 + col];
#pragma unroll
        for (int mf = 0; mf < 4; ++mf)
#pragma unroll
          for (int rr = 0; rr < 4; ++rr) {
            int r = mf*16 + kg*4 + rr;
            hdP[r*520 + col] = f2b(fmaxf(acc1[mf][nf][rr] + bb1, 0.f));
          }
      }
      __syncthreads();
#pragma unroll
      for (int kk = 0; kk < 2; ++kk) {
        bf16x8 a2[4], bw2[4];
#pragma unroll
        for (int mf = 0; mf < 4; ++mf)
          a2[mf] = *(const bf16x8*)&hdP[(mf*16 + rA)*520 + w*64 + kk*32 + kg*8];
#pragma unroll
        for (int nf = 0; nf < 4; ++nf)
          bw2[nf] = *(const bf16x8*)&w2l[(size_t)(nf*16 + rA)*1024 + kc*512 + w*64 + kk*32 + kg*8];
#pragma unroll
        for (int mf = 0; mf < 4; ++mf)
#pragma unroll
          for (int nf = 0; nf < 4; ++nf)
            acc2[mf][nf] = MFMA16(a2[mf], bw2[nf], acc2[mf][nf]);
      }
    }
    __syncthreads();
    float* P = (float*)hdP;
    if (w >= 4) {
      int slot = w - 4;
#pragma unroll
      for (int mf = 0; mf < 4; ++mf)
#pragma unroll
        for (int nf = 0; nf < 4; ++nf)
#pragma unroll
          for (int rr = 0; rr < 4; ++rr)
            P[slot*4160 + (mf*16 + kg*4 + rr)*65 + nf*16 + rA] = acc2[mf][nf][rr];
    }
    __syncthreads();
    if (w < 4) {
#pragma unroll
      for (int mf = 0; mf < 4; ++mf)
#pragma unroll
        for (int nf = 0; nf < 4; ++nf)
#pragma unroll
          for (int rr = 0; rr < 4; ++rr)
            P[w*4160 + (mf*16 + kg*4 + rr)*65 + nf*16 + rA] += acc2[mf][nf][rr];
    }
    __syncthreads();
    int r = t >> 3, j0 = (t & 7)*8;
    float x[8], s1 = 0.f, s2 = 0.f;
#pragma unroll
    for (int j = 0; j < 8; ++j) {
      int c = j0 + j;
      float xx = P[r*65 + c] + P[4160 + r*65 + c] + P[8320 + r*65 + c] + P[12480 + r*65 + c]
               + b2[layer*64 + c] + Af[r][c];
      x[j] = xx; s1 += xx; s2 += xx*xx;
    }
    s1 += __shfl_xor(s1, 1); s1 += __shfl_xor(s1, 2); s1 += __shfl_xor(s1, 4);
    s2 += __shfl_xor(s2, 1); s2 += __shfl_xor(s2, 2); s2 += __shfl_xor(s2, 4);
    float mean = s1 * (1.f/64.f);
    float var  = s2 * (1.f/64.f) - mean*mean;
    float rstd = rsqrtf(var + 1e-6f);
#pragma unroll
    for (int j = 0; j < 8; ++j) {
      int c = j0 + j;
      float nx = (x[j] - mean)*rstd*gl[layer*64 + c] + bel[layer*64 + c];
      Af[r][c] = nx;
      Afb[r][c] = f2b(nx);
      if (layer == 1) outB[OFF_A + (size_t)h*4096 + r*64 + c] = nx;
    }
    __syncthreads();
  }
  {
    int e = t & 63, dg = t >> 6;
    float pe = pwv[e], p = 0.f;
#pragma unroll
    for (int j = 0; j < 8; ++j) {
      int d = dg*8 + j;
      p += av[d] * powf(fabsf(Af[d][e]) + 1e-9f, pe);
    }
    red[dg][e] = p;
  }
  __syncthreads();
  if (t < 64) {
    float tot = 0.f;
#pragma unroll
    for (int g = 0; g < 8; ++g) tot += red[g][t];
    avApW[h*64 + t] = tot;
    outB[OFF_AVAP + h*64 + t] = tot;
  }
  if (h == 0) {
    if (t < 64) outB[OFF_PW + t] = pwv[t];
    if (t == 0) outB[OFF_BA] = bav[0];
  }
}

// ---------------- pass1: E/Ep (two-round LDS staging, nt) + softmax partials ----------------
__global__ __launch_bounds__(256) void k_pass1(
    const short* __restrict__ qh, const short* __restrict__ kh,
    const float* __restrict__ avAp, const float* __restrict__ mask,
    const float* __restrict__ bap, float* __restrict__ outB,
    float2* __restrict__ part) {
  __shared__ float Et[64*128];    // 32KB; phase A holds Qs/Ks bf16, phase B holds half E tile
  __shared__ float avl[64];
  short* Qs = (short*)Et;
  short* Ks = ((short*)Et) + 8192;
  int tt = blockIdx.x, st = blockIdx.y, h = blockIdx.z;
  int s0 = st*128, t0 = tt*128;
  int t = threadIdx.x, lane = t & 63;
  int wr = t >> 7, wc = (t >> 6) & 1;
  int rA = lane & 15, kg = lane >> 4;
  if (t < 16) *(f32x4*)&avl[t*4] = *(const f32x4*)&avAp[h*64 + t*4];
  __syncthreads();
#pragma unroll
  for (int i = 0; i < 4; ++i) {
    int cid = i*256 + t, row = cid >> 3, c = cid & 7, cs = c ^ (row & 7);
    union { int4 v; short s[8]; } qa, qo;
    qa.v = *(const int4*)&qh[((size_t)h*S_ + s0 + row)*DEP_ + c*8];
#pragma unroll
    for (int j = 0; j < 8; ++j) qo.s[j] = f2b(b2f(qa.s[j]) * avl[c*8 + j]);
    *(int4*)&Qs[row*64 + cs*8] = qo.v;
    *(int4*)&Ks[row*64 + cs*8] = *(const int4*)&kh[((size_t)h*S_ + t0 + row)*DEP_ + c*8];
  }
  __syncthreads();
  f32x4 acc[4][4] = {};
#pragma unroll
  for (int kk = 0; kk < 2; ++kk) {
    bf16x8 a[4], b[4];
#pragma unroll
    for (int m = 0; m < 4; ++m) {
      int row = wr*64 + m*16 + rA, c = (kk*4 + kg) ^ (row & 7);
      a[m] = *(const bf16x8*)&Qs[row*64 + c*8];
    }
#pragma unroll
    for (int n = 0; n < 4; ++n) {
      int row = wc*64 + n*16 + rA, c = (kk*4 + kg) ^ (row & 7);
      b[n] = *(const bf16x8*)&Ks[row*64 + c*8];
    }
#pragma unroll
    for (int m = 0; m < 4; ++m)
#pragma unroll
      for (int n = 0; n < 4; ++n)
        acc[m][n] = MFMA16(b[n], a[m], acc[m][n]);   // swapped: lane holds 4 consecutive t
  }
  float bav = bap[0];
  f32x4 mkf[4];
#pragma unroll
  for (int n = 0; n < 4; ++n) {
    f32x4 mm = *(const f32x4*)&mask[t0 + wc*64 + n*16 + kg*4];
#pragma unroll
    for (int j = 0; j < 4; ++j) mkf[n][j] = mm[j] * (-1e9f);
  }
#pragma unroll
  for (int m = 0; m < 4; ++m) {
    int row = s0 + wr*64 + m*16 + rA;
    float mx = -3.4e38f;
    f32x4 ep4[4];
#pragma unroll
    for (int n = 0; n < 4; ++n) {
      f32x4 e = acc[m][n];
      f32x4 ep;
#pragma unroll
      for (int j = 0; j < 4; ++j) {
        float ee = e[j];
        ep[j] = (ee > 0.f ? ee : 0.2f*ee) + bav + mkf[n][j];
        mx = fmaxf(mx, ep[j]);
      }
      ep4[n] = ep;
    }
    mx = fmaxf(mx, __shfl_xor(mx, 16));
    mx = fmaxf(mx, __shfl_xor(mx, 32));
    float sm = 0.f;
#pragma unroll
    for (int n = 0; n < 4; ++n)
#pragma unroll
      for (int j = 0; j < 4; ++j) sm += expf(ep4[n][j] - mx);
    sm += __shfl_xor(sm, 16);
    sm += __shfl_xor(sm, 32);
    if (kg == 0)
      part[((size_t)(h*S_ + row)*16 + tt)*2 + wc] = make_float2(mx, sm);
  }
  float* Eo  = outB + OFF_E;
  float* Epo = outB + OFF_EP;
  int colu = t & 31, rbase = t >> 5;
  f32x4 mm4 = *(const f32x4*)&mask[t0 + colu*4];
  f32x4 mk4;
#pragma unroll
  for (int j = 0; j < 4; ++j) mk4[j] = mm4[j] * (-1e9f);
  __syncthreads();
#pragma unroll
  for (int half = 0; half < 2; ++half) {
    if (wr == half) {
#pragma unroll
      for (int m = 0; m < 4; ++m)
#pragma unroll
        for (int n = 0; n < 4; ++n) {
          int row_l = m*16 + rA;
          int unit = wc*16 + n*4 + kg;
          *(f32x4*)&Et[row_l*128 + ((unit ^ (row_l & 7)))*4] = acc[m][n];
        }
    }
    __syncthreads();
#pragma unroll
    for (int r = 0; r < 8; ++r) {
      int row_l = r*8 + rbase;
      f32x4 e = *(const f32x4*)&Et[row_l*128 + ((colu ^ (row_l & 7)))*4];
      size_t gb = ((size_t)h*S_ + s0 + half*64 + row_l)*S_ + t0 + colu*4;
      st_nt(&Eo[gb], e);
      f32x4 ep;
#pragma unroll
      for (int j = 0; j < 4; ++j)
        ep[j] = (e[j] > 0.f ? e[j] : 0.2f*e[j]) + bav + mk4[j];
      st_nt(&Epo[gb], ep);
    }
    __syncthreads();
  }
}

// ---------------- pass2: fin-reduce prologue + attv (nt) + PV partial (staged Hn) ----------------
__global__ __launch_bounds__(256) void k_pass2(
    const short* __restrict__ qh, const short* __restrict__ kh,
    const short* __restrict__ vhT, const float* __restrict__ avAp,
    const float* __restrict__ mask, const float* __restrict__ bap,
    const float2* __restrict__ part, float* __restrict__ attv,
    short* __restrict__ Hnp0, short* __restrict__ Hnp1) {
  __shared__ short Qs[128*64];
  __shared__ __align__(16) short KP[128*128]; // kh tile / P tile (swz) / Hn staging
  __shared__ short Vs[64*128];
  __shared__ float avl[64];
  __shared__ float2 finS[128];
  int st = blockIdx.x, tc = blockIdx.y, h = blockIdx.z;
  int s0 = st * 128;
  int t = threadIdx.x, lane = t & 63;
  int wr = t >> 7, wc = (t >> 6) & 1;
  int rA = lane & 15, kg = lane >> 4;
  if (t < 16) *(f32x4*)&avl[t*4] = *(const f32x4*)&avAp[h*64 + t*4];
  if (t < 128) {
    const float2* pp = part + (size_t)(h*S_ + s0 + t) * 32;
    float M = -3.4e38f;
    for (int i = 0; i < 32; ++i) M = fmaxf(M, pp[i].x);
    float L = 0.f;
    for (int i = 0; i < 32; ++i) L += pp[i].y * expf(pp[i].x - M);
    finS[t] = make_float2(M, 1.f / L);
  }
  __syncthreads();
#pragma unroll
  for (int i = 0; i < 4; ++i) {
    int cid = i*256 + t, row = cid >> 3, c = cid & 7, cs = c ^ (row & 7);
    union { int4 v; short s[8]; } qa, qo;
    qa.v = *(const int4*)&qh[((size_t)h*S_ + s0 + row)*DEP_ + c*8];
#pragma unroll
    for (int j = 0; j < 8; ++j) qo.s[j] = f2b(b2f(qa.s[j]) * avl[c*8 + j]);
    *(int4*)&Qs[row*64 + cs*8] = qo.v;
  }
  float Ms[4], Li[4];
#pragma unroll
  for (int m = 0; m < 4; ++m) {
    float2 f = finS[wr*64 + m*16 + rA];
    Ms[m] = f.x; Li[m] = f.y;
  }
  float bav = bap[0];
  __syncthreads();
  bf16x8 aq[4][2];
#pragma unroll
  for (int m = 0; m < 4; ++m)
#pragma unroll
    for (int kk = 0; kk < 2; ++kk) {
      int row = wr*64 + m*16 + rA, c = (kk*4 + kg) ^ (row & 7);
      aq[m][kk] = *(const bf16x8*)&Qs[row*64 + c*8];
    }
  f32x4 acc2[4][2] = {};
  for (int tt = tc*8; tt < tc*8 + 8; ++tt) {
    int t0 = tt * 128;
    __syncthreads();    // prev iteration's P/V/attv reads done
#pragma unroll
    for (int i = 0; i < 4; ++i) {
      int cid = i*256 + t, row = cid >> 3, c = cid & 7, cs = c ^ (row & 7);
      *(int4*)&KP[row*64 + cs*8] = *(const int4*)&kh[((size_t)h*S_ + t0 + row)*DEP_ + c*8];
    }
#pragma unroll
    for (int i = 0; i < 4; ++i) {
      int cid = i*256 + t, row = cid >> 4, c = cid & 15, cs = c ^ (row & 7);
      *(int4*)&Vs[row*128 + cs*8] = *(const int4*)&vhT[((size_t)h*DEP_ + row)*S_ + t0 + c*8];
    }
    __syncthreads();
    f32x4 accE[4][4] = {};
#pragma unroll
    for (int kk = 0; kk < 2; ++kk) {
      bf16x8 b[4];
#pragma unroll
      for (int n = 0; n < 4; ++n) {
        int row = wc*64 + n*16 + rA, c = (kk*4 + kg) ^ (row & 7);
        b[n] = *(const bf16x8*)&KP[row*64 + c*8];
      }
#pragma unroll
      for (int m = 0; m < 4; ++m)
#pragma unroll
        for (int n = 0; n < 4; ++n)
          accE[m][n] = MFMA16(b[n], aq[m][kk], accE[m][n]);   // swapped
    }
    f32x4 mkf[4];
#pragma unroll
    for (int n = 0; n < 4; ++n) {
      f32x4 mm = *(const f32x4*)&mask[t0 + wc*64 + n*16 + kg*4];
#pragma unroll
      for (int j = 0; j < 4; ++j) mkf[n][j] = mm[j] * (-1e9f);
    }
#pragma unroll
    for (int m = 0; m < 4; ++m)
#pragma unroll
      for (int n = 0; n < 4; ++n) {
        f32x4 e = accE[m][n], p;
#pragma unroll
        for (int j = 0; j < 4; ++j) {
          float ep = (e[j] > 0.f ? e[j] : 0.2f*e[j]) + bav + mkf[n][j];
          p[j] = expf(ep - Ms[m]) * Li[m];
        }
        accE[m][n] = p;
      }
    __syncthreads();    // all KP(kh) fragment reads done before P overwrites
#pragma unroll
    for (int m = 0; m < 4; ++m) {
      int srow = wr*64 + m*16 + rA;
#pragma unroll
      for (int n = 0; n < 4; ++n) {
        int tcol = wc*64 + n*16 + kg*4;
        union { int2 v; short s[4]; } pk;
#pragma unroll
        for (int j = 0; j < 4; ++j) pk.s[j] = f2b(accE[m][n][j]);
        *(int2*)((char*)KP + srow*256 + ((tcol*2) ^ ((srow & 7) << 4))) = pk.v;
      }
    }
    __syncthreads();
#pragma unroll
    for (int kkp = 0; kkp < 4; ++kkp) {
      bf16x8 ap[4], bv[2];
#pragma unroll
      for (int m = 0; m < 4; ++m) {
        int row = wr*64 + m*16 + rA;
        ap[m] = *(const bf16x8*)((const char*)KP + row*256 + ((kkp*64 + kg*16) ^ ((row & 7) << 4)));
      }
#pragma unroll
      for (int n = 0; n < 2; ++n) {
        int dd = wc*32 + n*16 + rA, c = (kkp*4 + kg) ^ (dd & 7);
        bv[n] = *(const bf16x8*)&Vs[dd*128 + c*8];
      }
#pragma unroll
      for (int m = 0; m < 4; ++m)
#pragma unroll
        for (int n = 0; n < 2; ++n)
          acc2[m][n] = MFMA16(ap[m], bv[n], acc2[m][n]);
    }
    // attv coalesced store from the P-bf16 tile (values = f32(bf16(p)))
#pragma unroll
    for (int it = 0; it < 8; ++it) {
      int row = it*16 + (t >> 4);
      int unit = t & 15;
      union { int4 v; short s[8]; } pv;
      pv.v = *(const int4*)((const char*)KP + row*256 + ((unit*16) ^ ((row & 7) << 4)));
      f32x4 lo, hi;
#pragma unroll
      for (int j = 0; j < 4; ++j) { lo[j] = b2f(pv.s[j]); hi[j] = b2f(pv.s[4+j]); }
      size_t gb = ((size_t)h*S_ + s0 + row)*S_ + t0 + unit*8;
      st_nt(&attv[gb], lo);
      st_nt(&attv[gb + 4], hi);
    }
  }
  // stage Hn tile into KP (free now), then coalesced stores
  short* Hp = tc ? Hnp1 : Hnp0;
  short* Ht = KP;
  __syncthreads();   // last attv readback of KP done
#pragma unroll
  for (int m = 0; m < 4; ++m)
#pragma unroll
    for (int n = 0; n < 2; ++n) {
      int col = wc*32 + n*16 + rA;
#pragma unroll
      for (int rr = 0; rr < 4; ++rr) {
        int row = wr*64 + m*16 + kg*4 + rr;
        Ht[row*72 + col] = f2b(acc2[m][n][rr]);
      }
    }
  __syncthreads();
#pragma unroll
  for (int p = 0; p < 4; ++p) {
    int row = p*32 + (t >> 3), unit = t & 7;
    int4 vv = *(const int4*)&Ht[row*72 + unit*8];
    *(int4*)&Hp[(size_t)(s0 + row)*D_ + h*DEP_ + unit*8] = vv;
  }
}

extern "C" void kernel_launch(void* const* d_in, const int* in_sizes, int n_in,
                              void* d_out, int out_size, void* d_ws, size_t ws_size,
                              hipStream_t stream) {
  (void)in_sizes; (void)n_in; (void)out_size; (void)ws_size;
  const float* q    = (const float*)d_in[0];
  const float* k    = (const float*)d_in[1];
  const float* v    = (const float*)d_in[2];
  const float* mask = (const float*)d_in[3];
  const float* wq_w = (const float*)d_in[4];
  const float* wq_b = (const float*)d_in[5];
  const float* wk_w = (const float*)d_in[6];
  const float* wk_b = (const float*)d_in[7];
  const float* wv_w = (const float*)d_in[8];
  const float* wv_b = (const float*)d_in[9];
  const float* wo_w = (const float*)d_in[10];
  const float* wo_b = (const float*)d_in[11];
  const float* rl_w1 = (const float*)d_in[12];
  const float* rl_b1 = (const float*)d_in[13];
  const float* rl_w2 = (const float*)d_in[14];
  const float* rl_b2 = (const float*)d_in[15];
  const float* rl_g  = (const float*)d_in[16];
  const float* rl_be = (const float*)d_in[17];
  const float* pw    = (const float*)d_in[18];
  const float* avec  = (const float*)d_in[19];
  const float* ba    = (const float*)d_in[20];
  float* outf = (float*)d_out;

  // Workspace map (lifetime-based reuse, peak <= 32.5 MB)
  char* w = (char*)d_ws;
  short* xbf  = (short*)(w);                              // 0..12M  (dead after QKV gemm)
  short* wT   = (short*)(w + (12u << 20));                // 12..20M; woT @18M lives to end
  short* qh   = (short*)(w + (20u << 20));                // 20..24M (live to pass2)
  short* kh   = (short*)(w + (24u << 20));                // 24..28M (live to pass2)
  short* vh   = (short*)(w + (28u << 20));                // 28..32M (dead after transpose)
  short* qhT  = (short*)(w);                              // 0..4M   (dead after metric_p)
  short* vhT  = (short*)(w + (4u << 20));                 // 4..8M   (live to pass2)
  float* Apart = (float*)(w + (12u << 20));               // 2MB over wqT (dead after qkv)
  float2* part = (float2*)(w + (8u << 20));               // 8..16M  (written pass1, read pass2)
  float* avApW = (float*)(w + (16u << 20) + (512u << 10));// 4KB over wvT weight (dead)
  short* w1T  = (short*)(w + (32u << 20));                // 256KB (live until k_res)
  short* w2T  = (short*)(w + (32u << 20) + (256u << 10)); // 256KB
  short* Hnp0 = (short*)(w);                              // 0..4M  (over qhT, dead)
  short* Hnp1 = (short*)(w + (28u << 20));                // 28..32M (over vh, dead)

  k_cvt_all<<<dim3(7232), 256, 0, stream>>>(q, k, v, wq_w, wk_w, wv_w, wo_w,
                                            rl_w1, rl_w2, xbf, wT, w1T, w2T);
  k_gemm<<<dim3(16, 8, 3), 256, 0, stream>>>(xbf, nullptr, wT, wq_b, wk_b, wv_b,
                                             qh, nullptr, 0);
  k_transpose<<<dim3(32, 16, 2), 256, 0, stream>>>(qh, vh, qhT, vhT);
  k_metric_p<<<dim3(8, 16), 256, 0, stream>>>(qhT, Apart);
  k_res<<<dim3(16), 512, 0, stream>>>(Apart, w1T, rl_b1, w2T, rl_b2, rl_g, rl_be,
                                      pw, avec, ba, avApW, outf);
  k_pass1<<<dim3(16, 16, 16), 256, 0, stream>>>(qh, kh, avApW, mask, ba, outf, part);
  k_pass2<<<dim3(16, 2, 16), 256, 0, stream>>>(qh, kh, vhT, avApW, mask, ba, part,
                                               outf + OFF_ATT, Hnp0, Hnp1);
  k_gemm<<<dim3(16, 8, 1), 256, 0, stream>>>(Hnp0, Hnp1, wT + 3u*D_*D_,
                                             wo_b, wo_b, wo_b, nullptr, outf, 2);
}

// Round 9
// 468.915 us; speedup vs baseline: 1.1732x; 1.0131x over previous
//
#include <hip/hip_runtime.h>
#include <stdint.h>

#define S_ 2048
#define D_ 1024
#define H_ 16
#define DEP_ 64

typedef float f32x4 __attribute__((ext_vector_type(4)));
typedef __bf16 bf16x8 __attribute__((ext_vector_type(8)));

#define MFMA16(a,b,c) __builtin_amdgcn_mfma_f32_16x16x32_bf16((a),(b),(c),0,0,0)

// Output offsets (floats): (out, E, A, pw, attv, ba, avAp, Ep)
static constexpr size_t OFF_E    = 2097152ull;
static constexpr size_t OFF_A    = 69206016ull;
static constexpr size_t OFF_PW   = 69271552ull;
static constexpr size_t OFF_ATT  = 69271616ull;
static constexpr size_t OFF_BA   = 136380480ull;
static constexpr size_t OFF_AVAP = 136380481ull;
static constexpr size_t OFF_EP   = 136381505ull;

__device__ __forceinline__ short f2b(float f) {
  union { float f; uint32_t u; } c; c.f = f;
  uint32_t u = c.u;
  uint32_t r = (u + 0x7fffu + ((u >> 16) & 1u)) >> 16;
  return (short)(r & 0xffffu);
}
__device__ __forceinline__ float b2f(short s) {
  union { uint32_t u; float f; } c; c.u = ((uint32_t)(uint16_t)s) << 16;
  return c.f;
}
__device__ __forceinline__ void st_nt(float* p, f32x4 v) {
  __builtin_nontemporal_store(v, (f32x4*)p);
}

// ---------------- fused converts: inputs, proj weights, res weights ----------------
__global__ void k_cvt_all(const float* __restrict__ q, const float* __restrict__ k,
                          const float* __restrict__ v, const float* __restrict__ wq,
                          const float* __restrict__ wk, const float* __restrict__ wv,
                          const float* __restrict__ wo, const float* __restrict__ w1,
                          const float* __restrict__ w2, short* __restrict__ xbf,
                          short* __restrict__ wT, short* __restrict__ w1T,
                          short* __restrict__ w2T) {
  __shared__ float tile[64][65];
  int bid = blockIdx.x, t = threadIdx.x;
  if (bid < 6144) {
    int z = bid >> 11, bx = bid & 2047;
    const float* src = (z == 0) ? q : (z == 1) ? k : v;
    short* d = xbf + (size_t)z * (S_*D_);
    int i = (bx*256 + t)*4;
    float4 f = *(const float4*)(src + i);
    short4 o;
    o.x = f2b(f.x); o.y = f2b(f.y); o.z = f2b(f.z); o.w = f2b(f.w);
    *(short4*)(d + i) = o;
  } else if (bid < 7168) {
    int u = bid - 6144, z = u >> 8, tl = u & 255;
    int k0 = (tl >> 4)*64, n0 = (tl & 15)*64;
    const float* W = (z == 0) ? wq : (z == 1) ? wk : (z == 2) ? wv : wo;
    short* d = wT + (size_t)z * (D_*D_);
    for (int i = 0; i < 16; ++i) {
      int e = i*256 + t, r = e >> 6, c = e & 63;
      tile[r][c] = W[(size_t)(k0+r)*D_ + n0 + c];
    }
    __syncthreads();
    for (int i = 0; i < 16; ++i) {
      int e = i*256 + t, r = e >> 6, c = e & 63;
      d[(size_t)(n0+r)*D_ + k0 + c] = f2b(tile[c][r]);
    }
  } else {
    int u = bid - 7168, z = u >> 4, bx = u & 15;
    int l = z >> 1, which = z & 1;
    if (which == 0) {
      const float* src = w1 + (size_t)l*65536;
      short* d = w1T + (size_t)l*65536;
      int n0 = bx*64;
      for (int i = 0; i < 16; ++i) {
        int e = i*256 + t, r = e >> 6, c = e & 63;
        tile[r][c] = src[(size_t)r*1024 + n0 + c];
      }
      __syncthreads();
      for (int i = 0; i < 16; ++i) {
        int e = i*256 + t, r = e >> 6, c = e & 63;
        d[(size_t)(n0+r)*64 + c] = f2b(tile[c][r]);
      }
    } else {
      const float* src = w2 + (size_t)l*65536;
      short* d = w2T + (size_t)l*65536;
      int k0 = bx*64;
      for (int i = 0; i < 16; ++i) {
        int e = i*256 + t, r = e >> 6, c = e & 63;
        tile[r][c] = src[(size_t)(k0+r)*64 + c];
      }
      __syncthreads();
      for (int i = 0; i < 16; ++i) {
        int e = i*256 + t, r = e >> 6, c = e & 63;
        d[(size_t)r*1024 + k0 + c] = f2b(tile[c][r]);
      }
    }
  }
}

// ---------------- 128x128 bf16 GEMM: C = X @ WT^T + bias ----------------
// mode 0: write bf16 head-major (LDS-staged); mode 2: X = X+X2+X3+X4 (bf16), write f32 outf
__global__ __launch_bounds__(256) void k_gemm(
    const short* __restrict__ Xall, const short* __restrict__ X2,
    const short* __restrict__ X3, const short* __restrict__ X4,
    const short* __restrict__ WTall,
    const float* __restrict__ b0, const float* __restrict__ b1v,
    const float* __restrict__ b2v, short* __restrict__ dstall,
    float* __restrict__ outf, int mode) {
  __shared__ __align__(16) short SS[2*128*72];   // As/Bs in K-loop; C staging after
  short* As = SS;
  short* Bs = SS + 128*72;
  int z = blockIdx.z;
  const short* X  = Xall + (size_t)z * (S_*D_);
  const short* WT = WTall + (size_t)z * (D_*D_);
  int m0 = blockIdx.x * 128, n0 = blockIdx.y * 128;
  int t = threadIdx.x, lane = t & 63;
  int wr = t >> 7, wc = (t >> 6) & 1;
  int rA = lane & 15, kg = lane >> 4;
  f32x4 acc[4][4] = {};
  for (int kt = 0; kt < 16; ++kt) {
#pragma unroll
    for (int i = 0; i < 4; ++i) {
      int cid = i*256 + t, row = cid >> 3, c = cid & 7;
      size_t xi = (size_t)(m0+row)*D_ + kt*64 + c*8;
      if (mode == 2) {
        union { int4 v; short s[8]; } a1, a2, a3, a4, o;
        a1.v = *(const int4*)&X[xi];
        a2.v = *(const int4*)&X2[xi];
        a3.v = *(const int4*)&X3[xi];
        a4.v = *(const int4*)&X4[xi];
#pragma unroll
        for (int j = 0; j < 8; ++j)
          o.s[j] = f2b(b2f(a1.s[j]) + b2f(a2.s[j]) + b2f(a3.s[j]) + b2f(a4.s[j]));
        *(int4*)&As[row*72 + c*8] = o.v;
      } else {
        *(int4*)&As[row*72 + c*8] = *(const int4*)&X[xi];
      }
      *(int4*)&Bs[row*72 + c*8] = *(const int4*)&WT[(size_t)(n0+row)*D_ + kt*64 + c*8];
    }
    __syncthreads();
#pragma unroll
    for (int kk = 0; kk < 2; ++kk) {
      bf16x8 a[4], b[4];
#pragma unroll
      for (int m = 0; m < 4; ++m)
        a[m] = *(const bf16x8*)&As[(wr*64 + m*16 + rA)*72 + kk*32 + kg*8];
#pragma unroll
      for (int n = 0; n < 4; ++n)
        b[n] = *(const bf16x8*)&Bs[(wc*64 + n*16 + rA)*72 + kk*32 + kg*8];
#pragma unroll
      for (int m = 0; m < 4; ++m)
#pragma unroll
        for (int n = 0; n < 4; ++n)
          acc[m][n] = MFMA16(a[m], b[n], acc[m][n]);
    }
    __syncthreads();
  }
  const float* bias = (mode != 0) ? b0 : (z == 0 ? b0 : (z == 1 ? b1v : b2v));
  if (mode == 0) {
    short* Ct = SS;
#pragma unroll
    for (int m = 0; m < 4; ++m)
#pragma unroll
      for (int n = 0; n < 4; ++n) {
        int col = wc*64 + n*16 + rA;
        float bb = bias[n0 + col];
#pragma unroll
        for (int rr = 0; rr < 4; ++rr) {
          int row = wr*64 + m*16 + kg*4 + rr;
          Ct[row*136 + col] = f2b(acc[m][n][rr] + bb);
        }
      }
    __syncthreads();
#pragma unroll
    for (int p = 0; p < 8; ++p) {
      int row = p*16 + (t >> 4), unit = t & 15;
      int4 vv = *(const int4*)&Ct[row*136 + unit*8];
      int gcol = n0 + unit*8;
      int head = gcol >> 6, dd = gcol & 63;
      *(int4*)&dstall[(size_t)z*(S_*D_) + ((size_t)head*S_ + m0 + row)*DEP_ + dd] = vv;
    }
  } else {
    float* Ct = (float*)SS;
#pragma unroll
    for (int half = 0; half < 2; ++half) {
      if (wr == half) {
#pragma unroll
        for (int m = 0; m < 4; ++m)
#pragma unroll
          for (int n = 0; n < 4; ++n) {
            int col = wc*64 + n*16 + rA;
            float bb = bias[n0 + col];
#pragma unroll
            for (int rr = 0; rr < 4; ++rr)
              Ct[(m*16 + kg*4 + rr)*132 + col] = acc[m][n][rr] + bb;
          }
      }
      __syncthreads();
#pragma unroll
      for (int p = 0; p < 8; ++p) {
        int row_l = p*8 + (t >> 5), unit = t & 31;
        f32x4 vv = *(const f32x4*)&Ct[row_l*132 + unit*4];
        st_nt(&outf[(size_t)(m0 + half*64 + row_l)*D_ + n0 + unit*4], vv);
      }
      __syncthreads();
    }
  }
}

// ---------------- bf16 transpose [h][S][64] -> [h][64][S] ----------------
__global__ void k_transpose(const short* __restrict__ qh, const short* __restrict__ vh,
                            short* __restrict__ qhT, short* __restrict__ vhT) {
  __shared__ short tile[64][68];
  const short* src = blockIdx.z ? vh : qh;
  short* dst = blockIdx.z ? vhT : qhT;
  int h = blockIdx.y, s0 = blockIdx.x * 64, t = threadIdx.x;
  for (int i = 0; i < 16; ++i) {
    int e = i*256 + t, r = e >> 6, c = e & 63;
    tile[r][c] = src[((size_t)h*S_ + s0 + r)*DEP_ + c];
  }
  __syncthreads();
  for (int i = 0; i < 16; ++i) {
    int e = i*256 + t, r = e >> 6, c = e & 63;
    dst[((size_t)h*DEP_ + r)*S_ + s0 + c] = tile[c][r];
  }
}

// ---------------- metric partial ----------------
__global__ __launch_bounds__(256) void k_metric_p(const short* __restrict__ qhT,
                                                  float* __restrict__ Apart) {
  __shared__ short qt[64*72];
  int kc = blockIdx.x, h = blockIdx.y, t = threadIdx.x, lane = t & 63;
  int wr = t >> 7, wc = (t >> 6) & 1;
  int rA = lane & 15, kg = lane >> 4;
  f32x4 acc[2][2] = {};
  for (int kt = 0; kt < 4; ++kt) {
#pragma unroll
    for (int i = 0; i < 2; ++i) {
      int cid = i*256 + t, row = cid >> 3, c = cid & 7;
      *(int4*)&qt[row*72 + c*8] =
        *(const int4*)&qhT[((size_t)h*DEP_ + row)*S_ + kc*256 + kt*64 + c*8];
    }
    __syncthreads();
#pragma unroll
    for (int kk = 0; kk < 2; ++kk) {
      bf16x8 a[2], b[2];
#pragma unroll
      for (int m = 0; m < 2; ++m)
        a[m] = *(const bf16x8*)&qt[(wr*32 + m*16 + rA)*72 + kk*32 + kg*8];
#pragma unroll
      for (int n = 0; n < 2; ++n)
        b[n] = *(const bf16x8*)&qt[(wc*32 + n*16 + rA)*72 + kk*32 + kg*8];
#pragma unroll
      for (int m = 0; m < 2; ++m)
#pragma unroll
        for (int n = 0; n < 2; ++n)
          acc[m][n] = MFMA16(a[m], b[n], acc[m][n]);
    }
    __syncthreads();
  }
#pragma unroll
  for (int m = 0; m < 2; ++m)
#pragma unroll
    for (int n = 0; n < 2; ++n)
#pragma unroll
      for (int rr = 0; rr < 4; ++rr) {
        int row = wr*32 + m*16 + kg*4 + rr, col = wc*32 + n*16 + rA;
        Apart[((size_t)(kc*16 + h))*4096 + row*64 + col] = acc[m][n][rr];
      }
}

// ---------------- fused res stack: metric reduce + 2x(d1+d2+LN) + avAp ----------------
__global__ __launch_bounds__(512) void k_res(
    const float* __restrict__ Apart, const short* __restrict__ w1T,
    const float* __restrict__ b1, const short* __restrict__ w2T,
    const float* __restrict__ b2, const float* __restrict__ gl,
    const float* __restrict__ bel, const float* __restrict__ pwv,
    const float* __restrict__ av, const float* __restrict__ bav,
    float* __restrict__ avApW, float* __restrict__ outB) {
  __shared__ float Af[64][68];
  __shared__ short Afb[64][72];
  __shared__ short hdP[64*520];
  __shared__ float red[8][64];
  int h = blockIdx.x, t = threadIdx.x;
  int lane = t & 63, w = t >> 6;
  int rA = lane & 15, kg = lane >> 4;
#pragma unroll
  for (int i = 0; i < 2; ++i) {
    int idx = (i*512 + t)*4;
    f32x4 s = {};
#pragma unroll
    for (int kc = 0; kc < 8; ++kc)
      s += *(const f32x4*)&Apart[((size_t)(kc*16 + h))*4096 + idx];
    int r = idx >> 6, c = idx & 63;
    *(f32x4*)&Af[r][c] = s;
    union { int2 v; short sh[4]; } pk;
#pragma unroll
    for (int j = 0; j < 4; ++j) pk.sh[j] = f2b(s[j]);
    *(int2*)&Afb[r][c] = pk.v;
  }
  __syncthreads();
  for (int layer = 0; layer < 2; ++layer) {
    const short* w1l = w1T + layer*65536;
    const short* w2l = w2T + layer*65536;
    f32x4 acc2[4][4] = {};
    for (int kc = 0; kc < 2; ++kc) {
      int c0g = kc*512 + w*64;
      f32x4 acc1[4][4] = {};
#pragma unroll
      for (int kk = 0; kk < 2; ++kk) {
        bf16x8 aA[4], bW[4];
#pragma unroll
        for (int mf = 0; mf < 4; ++mf)
          aA[mf] = *(const bf16x8*)&Afb[mf*16 + rA][kk*32 + kg*8];
#pragma unroll
        for (int nf = 0; nf < 4; ++nf)
          bW[nf] = *(const bf16x8*)&w1l[(size_t)(c0g + nf*16 + rA)*64 + kk*32 + kg*8];
#pragma unroll
        for (int mf = 0; mf < 4; ++mf)
#pragma unroll
          for (int nf = 0; nf < 4; ++nf)
            acc1[mf][nf] = MFMA16(aA[mf], bW[nf], acc1[mf][nf]);
      }
      __syncthreads();
#pragma unroll
      for (int nf = 0; nf < 4; ++nf) {
        int col = w*64 + nf*16 + rA;
        float bb1 = b1[layer*1024 + kc*512 + col];
#pragma unroll
        for (int mf = 0; mf < 4; ++mf)
#pragma unroll
          for (int rr = 0; rr < 4; ++rr) {
            int r = mf*16 + kg*4 + rr;
            hdP[r*520 + col] = f2b(fmaxf(acc1[mf][nf][rr] + bb1, 0.f));
          }
      }
      __syncthreads();
#pragma unroll
      for (int kk = 0; kk < 2; ++kk) {
        bf16x8 a2[4], bw2[4];
#pragma unroll
        for (int mf = 0; mf < 4; ++mf)
          a2[mf] = *(const bf16x8*)&hdP[(mf*16 + rA)*520 + w*64 + kk*32 + kg*8];
#pragma unroll
        for (int nf = 0; nf < 4; ++nf)
          bw2[nf] = *(const bf16x8*)&w2l[(size_t)(nf*16 + rA)*1024 + kc*512 + w*64 + kk*32 + kg*8];
#pragma unroll
        for (int mf = 0; mf < 4; ++mf)
#pragma unroll
          for (int nf = 0; nf < 4; ++nf)
            acc2[mf][nf] = MFMA16(a2[mf], bw2[nf], acc2[mf][nf]);
      }
    }
    __syncthreads();
    float* P = (float*)hdP;
    if (w >= 4) {
      int slot = w - 4;
#pragma unroll
      for (int mf = 0; mf < 4; ++mf)
#pragma unroll
        for (int nf = 0; nf < 4; ++nf)
#pragma unroll
          for (int rr = 0; rr < 4; ++rr)
            P[slot*4160 + (mf*16 + kg*4 + rr)*65 + nf*16 + rA] = acc2[mf][nf][rr];
    }
    __syncthreads();
    if (w < 4) {
#pragma unroll
      for (int mf = 0; mf < 4; ++mf)
#pragma unroll
        for (int nf = 0; nf < 4; ++nf)
#pragma unroll
          for (int rr = 0; rr < 4; ++rr)
            P[w*4160 + (mf*16 + kg*4 + rr)*65 + nf*16 + rA] += acc2[mf][nf][rr];
    }
    __syncthreads();
    int r = t >> 3, j0 = (t & 7)*8;
    float x[8], s1 = 0.f, s2 = 0.f;
#pragma unroll
    for (int j = 0; j < 8; ++j) {
      int c = j0 + j;
      float xx = P[r*65 + c] + P[4160 + r*65 + c] + P[8320 + r*65 + c] + P[12480 + r*65 + c]
               + b2[layer*64 + c] + Af[r][c];
      x[j] = xx; s1 += xx; s2 += xx*xx;
    }
    s1 += __shfl_xor(s1, 1); s1 += __shfl_xor(s1, 2); s1 += __shfl_xor(s1, 4);
    s2 += __shfl_xor(s2, 1); s2 += __shfl_xor(s2, 2); s2 += __shfl_xor(s2, 4);
    float mean = s1 * (1.f/64.f);
    float var  = s2 * (1.f/64.f) - mean*mean;
    float rstd = rsqrtf(var + 1e-6f);
#pragma unroll
    for (int j = 0; j < 8; ++j) {
      int c = j0 + j;
      float nx = (x[j] - mean)*rstd*gl[layer*64 + c] + bel[layer*64 + c];
      Af[r][c] = nx;
      Afb[r][c] = f2b(nx);
      if (layer == 1) outB[OFF_A + (size_t)h*4096 + r*64 + c] = nx;
    }
    __syncthreads();
  }
  {
    int e = t & 63, dg = t >> 6;
    float pe = pwv[e], p = 0.f;
#pragma unroll
    for (int j = 0; j < 8; ++j) {
      int d = dg*8 + j;
      p += av[d] * powf(fabsf(Af[d][e]) + 1e-9f, pe);
    }
    red[dg][e] = p;
  }
  __syncthreads();
  if (t < 64) {
    float tot = 0.f;
#pragma unroll
    for (int g = 0; g < 8; ++g) tot += red[g][t];
    avApW[h*64 + t] = tot;
    outB[OFF_AVAP + h*64 + t] = tot;
  }
  if (h == 0) {
    if (t < 64) outB[OFF_PW + t] = pwv[t];
    if (t == 0) outB[OFF_BA] = bav[0];
  }
}

// ---------------- pass1: 64-row tiles, E/Ep staged nt stores + per-tile stats ----------------
__global__ __launch_bounds__(256) void k_pass1(
    const short* __restrict__ qh, const short* __restrict__ kh,
    const float* __restrict__ avAp, const float* __restrict__ mask,
    const float* __restrict__ bap, float* __restrict__ outB,
    float2* __restrict__ part) {
  __shared__ float Et[64*128];     // 32KB union: Qs(8K)+Ks(16K) | E f32 tile
  __shared__ float2 red[4][64];
  __shared__ float avl[64];
  short* Qs = (short*)Et;          // [0, 8K)
  short* Ks = ((short*)Et) + 4096; // [8K, 24K)
  int tt = blockIdx.x, sb = blockIdx.y, h = blockIdx.z;
  int s0 = sb*64, t0 = tt*128;
  int t = threadIdx.x, lane = t & 63, w = t >> 6;
  int rA = lane & 15, kg = lane >> 4;
  if (t < 16) *(f32x4*)&avl[t*4] = *(const f32x4*)&avAp[h*64 + t*4];
  __syncthreads();
  // load 64 q rows + 128 k rows
#pragma unroll
  for (int i = 0; i < 6; ++i) {
    int cid = i*256 + t, row = cid >> 3, c = cid & 7, cs = c ^ (row & 7);
    if (row < 64) {
      union { int4 v; short s[8]; } qa, qo;
      qa.v = *(const int4*)&qh[((size_t)h*S_ + s0 + row)*DEP_ + c*8];
#pragma unroll
      for (int j = 0; j < 8; ++j) qo.s[j] = f2b(b2f(qa.s[j]) * avl[c*8 + j]);
      *(int4*)&Qs[row*64 + cs*8] = qo.v;
    } else {
      int kr = row - 64, csk = c ^ (kr & 7);
      *(int4*)&Ks[kr*64 + csk*8] = *(const int4*)&kh[((size_t)h*S_ + t0 + kr)*DEP_ + c*8];
    }
  }
  __syncthreads();
  f32x4 acc[4][2] = {};
#pragma unroll
  for (int kk = 0; kk < 2; ++kk) {
    bf16x8 a[4], b[2];
#pragma unroll
    for (int m = 0; m < 4; ++m) {
      int row = m*16 + rA, c = (kk*4 + kg) ^ (row & 7);
      a[m] = *(const bf16x8*)&Qs[row*64 + c*8];
    }
#pragma unroll
    for (int n = 0; n < 2; ++n) {
      int kr = w*32 + n*16 + rA, c = (kk*4 + kg) ^ (kr & 7);
      b[n] = *(const bf16x8*)&Ks[kr*64 + c*8];
    }
#pragma unroll
    for (int m = 0; m < 4; ++m)
#pragma unroll
      for (int n = 0; n < 2; ++n)
        acc[m][n] = MFMA16(b[n], a[m], acc[m][n]);   // row=m*16+rA, col=w*32+n*16+kg*4+j
  }
  // per-wave stats for its 32-col slice
  float bav = bap[0];
  f32x4 mkf[2];
#pragma unroll
  for (int n = 0; n < 2; ++n) {
    f32x4 mm = *(const f32x4*)&mask[t0 + w*32 + n*16 + kg*4];
#pragma unroll
    for (int j = 0; j < 4; ++j) mkf[n][j] = mm[j] * (-1e9f);
  }
#pragma unroll
  for (int m = 0; m < 4; ++m) {
    float mx = -3.4e38f;
    f32x4 ep4[2];
#pragma unroll
    for (int n = 0; n < 2; ++n) {
      f32x4 e = acc[m][n];
      f32x4 ep;
#pragma unroll
      for (int j = 0; j < 4; ++j) {
        float ee = e[j];
        ep[j] = (ee > 0.f ? ee : 0.2f*ee) + bav + mkf[n][j];
        mx = fmaxf(mx, ep[j]);
      }
      ep4[n] = ep;
    }
    mx = fmaxf(mx, __shfl_xor(mx, 16));
    mx = fmaxf(mx, __shfl_xor(mx, 32));
    float sm = 0.f;
#pragma unroll
    for (int n = 0; n < 2; ++n)
#pragma unroll
      for (int j = 0; j < 4; ++j) sm += expf(ep4[n][j] - mx);
    sm += __shfl_xor(sm, 16);
    sm += __shfl_xor(sm, 32);
    if (kg == 0) red[w][m*16 + rA] = make_float2(mx, sm);
  }
  __syncthreads();   // red ready; also all Qs/Ks reads done
  if (t < 64) {
    float M = red[0][t].x;
#pragma unroll
    for (int g = 1; g < 4; ++g) M = fmaxf(M, red[g][t].x);
    float L = 0.f;
#pragma unroll
    for (int g = 0; g < 4; ++g) L += red[g][t].y * expf(red[g][t].x - M);
    part[((size_t)(h*S_ + s0 + t))*16 + tt] = make_float2(M, L);
  }
  // stage E tile (swizzled 16B units)
#pragma unroll
  for (int m = 0; m < 4; ++m)
#pragma unroll
    for (int n = 0; n < 2; ++n) {
      int row = m*16 + rA;
      int unit = w*8 + n*4 + kg;
      *(f32x4*)&Et[row*128 + ((unit ^ (row & 7)))*4] = acc[m][n];
    }
  __syncthreads();
  // coalesced readback: E + Ep
  float* Eo  = outB + OFF_E;
  float* Epo = outB + OFF_EP;
  int colu = t & 31, rbase = t >> 5;
  f32x4 mm4 = *(const f32x4*)&mask[t0 + colu*4];
  f32x4 mk4;
#pragma unroll
  for (int j = 0; j < 4; ++j) mk4[j] = mm4[j] * (-1e9f);
#pragma unroll
  for (int r = 0; r < 8; ++r) {
    int row = r*8 + rbase;
    f32x4 e = *(const f32x4*)&Et[row*128 + ((colu ^ (row & 7)))*4];
    size_t gb = ((size_t)h*S_ + s0 + row)*S_ + t0 + colu*4;
    st_nt(&Eo[gb], e);
    f32x4 ep;
#pragma unroll
    for (int j = 0; j < 4; ++j)
      ep[j] = (e[j] > 0.f ? e[j] : 0.2f*e[j]) + bav + mk4[j];
    st_nt(&Epo[gb], ep);
  }
}

// ---------------- softmax stats reduce ----------------
__global__ void k_sreduce(const float2* __restrict__ part, float2* __restrict__ fin) {
  int row = blockIdx.x * 256 + threadIdx.x;
  const float2* pp = part + (size_t)row * 16;
  float2 p[16];
  float M = -3.4e38f;
#pragma unroll
  for (int i = 0; i < 16; ++i) { p[i] = pp[i]; M = fmaxf(M, p[i].x); }
  float L = 0.f;
#pragma unroll
  for (int i = 0; i < 16; ++i) L += p[i].y * expf(p[i].x - M);
  fin[row] = make_float2(M, L);
}

// ---------------- pass2: attv (nt) + PV partial (staged Hn), tc=4 ----------------
__global__ __launch_bounds__(256) void k_pass2(
    const short* __restrict__ qh, const short* __restrict__ kh,
    const short* __restrict__ vhT, const float* __restrict__ avAp,
    const float* __restrict__ mask, const float* __restrict__ bap,
    const float2* __restrict__ fin, float* __restrict__ attv,
    short* __restrict__ Hnp0, short* __restrict__ Hnp1,
    short* __restrict__ Hnp2, short* __restrict__ Hnp3) {
  __shared__ short Qs[128*64];
  __shared__ __align__(16) short KP[128*128]; // kh tile / P tile (swz) / Hn staging
  __shared__ short Vs[64*128];
  __shared__ float avl[64];
  int st = blockIdx.x, tc = blockIdx.y, h = blockIdx.z;
  int s0 = st * 128;
  int t = threadIdx.x, lane = t & 63;
  int wr = t >> 7, wc = (t >> 6) & 1;
  int rA = lane & 15, kg = lane >> 4;
  if (t < 16) *(f32x4*)&avl[t*4] = *(const f32x4*)&avAp[h*64 + t*4];
  __syncthreads();
#pragma unroll
  for (int i = 0; i < 4; ++i) {
    int cid = i*256 + t, row = cid >> 3, c = cid & 7, cs = c ^ (row & 7);
    union { int4 v; short s[8]; } qa, qo;
    qa.v = *(const int4*)&qh[((size_t)h*S_ + s0 + row)*DEP_ + c*8];
#pragma unroll
    for (int j = 0; j < 8; ++j) qo.s[j] = f2b(b2f(qa.s[j]) * avl[c*8 + j]);
    *(int4*)&Qs[row*64 + cs*8] = qo.v;
  }
  float Ms[4], Li[4];
#pragma unroll
  for (int m = 0; m < 4; ++m) {
    float2 f = fin[h*S_ + s0 + wr*64 + m*16 + rA];
    Ms[m] = f.x; Li[m] = 1.f / f.y;
  }
  float bav = bap[0];
  __syncthreads();
  bf16x8 aq[4][2];
#pragma unroll
  for (int m = 0; m < 4; ++m)
#pragma unroll
    for (int kk = 0; kk < 2; ++kk) {
      int row = wr*64 + m*16 + rA, c = (kk*4 + kg) ^ (row & 7);
      aq[m][kk] = *(const bf16x8*)&Qs[row*64 + c*8];
    }
  f32x4 acc2[4][2] = {};
  for (int tt = tc*4; tt < tc*4 + 4; ++tt) {
    int t0 = tt * 128;
    __syncthreads();    // prev iteration's P/attv/V reads done
#pragma unroll
    for (int i = 0; i < 4; ++i) {
      int cid = i*256 + t, row = cid >> 3, c = cid & 7, cs = c ^ (row & 7);
      *(int4*)&KP[row*64 + cs*8] = *(const int4*)&kh[((size_t)h*S_ + t0 + row)*DEP_ + c*8];
    }
#pragma unroll
    for (int i = 0; i < 4; ++i) {
      int cid = i*256 + t, row = cid >> 4, c = cid & 15, cs = c ^ (row & 7);
      *(int4*)&Vs[row*128 + cs*8] = *(const int4*)&vhT[((size_t)h*DEP_ + row)*S_ + t0 + c*8];
    }
    __syncthreads();
    f32x4 accE[4][4] = {};
#pragma unroll
    for (int kk = 0; kk < 2; ++kk) {
      bf16x8 b[4];
#pragma unroll
      for (int n = 0; n < 4; ++n) {
        int row = wc*64 + n*16 + rA, c = (kk*4 + kg) ^ (row & 7);
        b[n] = *(const bf16x8*)&KP[row*64 + c*8];
      }
#pragma unroll
      for (int m = 0; m < 4; ++m)
#pragma unroll
        for (int n = 0; n < 4; ++n)
          accE[m][n] = MFMA16(b[n], aq[m][kk], accE[m][n]);   // swapped
    }
    f32x4 mkf[4];
#pragma unroll
    for (int n = 0; n < 4; ++n) {
      f32x4 mm = *(const f32x4*)&mask[t0 + wc*64 + n*16 + kg*4];
#pragma unroll
      for (int j = 0; j < 4; ++j) mkf[n][j] = mm[j] * (-1e9f);
    }
#pragma unroll
    for (int m = 0; m < 4; ++m)
#pragma unroll
      for (int n = 0; n < 4; ++n) {
        f32x4 e = accE[m][n], p;
#pragma unroll
        for (int j = 0; j < 4; ++j) {
          float ep = (e[j] > 0.f ? e[j] : 0.2f*e[j]) + bav + mkf[n][j];
          p[j] = expf(ep - Ms[m]) * Li[m];
        }
        accE[m][n] = p;
      }
    __syncthreads();    // all KP(kh) fragment reads done before P overwrites
#pragma unroll
    for (int m = 0; m < 4; ++m) {
      int srow = wr*64 + m*16 + rA;
#pragma unroll
      for (int n = 0; n < 4; ++n) {
        int tcol = wc*64 + n*16 + kg*4;
        union { int2 v; short s[4]; } pk;
#pragma unroll
        for (int j = 0; j < 4; ++j) pk.s[j] = f2b(accE[m][n][j]);
        *(int2*)((char*)KP + srow*256 + ((tcol*2) ^ ((srow & 7) << 4))) = pk.v;
      }
    }
    __syncthreads();
#pragma unroll
    for (int kkp = 0; kkp < 4; ++kkp) {
      bf16x8 ap[4], bv[2];
#pragma unroll
      for (int m = 0; m < 4; ++m) {
        int row = wr*64 + m*16 + rA;
        ap[m] = *(const bf16x8*)((const char*)KP + row*256 + ((kkp*64 + kg*16) ^ ((row & 7) << 4)));
      }
#pragma unroll
      for (int n = 0; n < 2; ++n) {
        int dd = wc*32 + n*16 + rA, c = (kkp*4 + kg) ^ (dd & 7);
        bv[n] = *(const bf16x8*)&Vs[dd*128 + c*8];
      }
#pragma unroll
      for (int m = 0; m < 4; ++m)
#pragma unroll
        for (int n = 0; n < 2; ++n)
          acc2[m][n] = MFMA16(ap[m], bv[n], acc2[m][n]);
    }
    // attv coalesced store from the P-bf16 tile (values = f32(bf16(p)))
#pragma unroll
    for (int it = 0; it < 8; ++it) {
      int row = it*16 + (t >> 4);
      int unit = t & 15;
      union { int4 v; short s[8]; } pv;
      pv.v = *(const int4*)((const char*)KP + row*256 + ((unit*16) ^ ((row & 7) << 4)));
      f32x4 lo, hi;
#pragma unroll
      for (int j = 0; j < 4; ++j) { lo[j] = b2f(pv.s[j]); hi[j] = b2f(pv.s[4+j]); }
      size_t gb = ((size_t)h*S_ + s0 + row)*S_ + t0 + unit*8;
      st_nt(&attv[gb], lo);
      st_nt(&attv[gb + 4], hi);
    }
  }
  // stage Hn tile into KP, then coalesced stores
  short* Hp = (tc == 0) ? Hnp0 : (tc == 1) ? Hnp1 : (tc == 2) ? Hnp2 : Hnp3;
  short* Ht = KP;
  __syncthreads();
#pragma unroll
  for (int m = 0; m < 4; ++m)
#pragma unroll
    for (int n = 0; n < 2; ++n) {
      int col = wc*32 + n*16 + rA;
#pragma unroll
      for (int rr = 0; rr < 4; ++rr) {
        int row = wr*64 + m*16 + kg*4 + rr;
        Ht[row*72 + col] = f2b(acc2[m][n][rr]);
      }
    }
  __syncthreads();
#pragma unroll
  for (int p = 0; p < 4; ++p) {
    int row = p*32 + (t >> 3), unit = t & 7;
    int4 vv = *(const int4*)&Ht[row*72 + unit*8];
    *(int4*)&Hp[(size_t)(s0 + row)*D_ + h*DEP_ + unit*8] = vv;
  }
}

extern "C" void kernel_launch(void* const* d_in, const int* in_sizes, int n_in,
                              void* d_out, int out_size, void* d_ws, size_t ws_size,
                              hipStream_t stream) {
  (void)in_sizes; (void)n_in; (void)out_size; (void)ws_size;
  const float* q    = (const float*)d_in[0];
  const float* k    = (const float*)d_in[1];
  const float* v    = (const float*)d_in[2];
  const float* mask = (const float*)d_in[3];
  const float* wq_w = (const float*)d_in[4];
  const float* wq_b = (const float*)d_in[5];
  const float* wk_w = (const float*)d_in[6];
  const float* wk_b = (const float*)d_in[7];
  const float* wv_w = (const float*)d_in[8];
  const float* wv_b = (const float*)d_in[9];
  const float* wo_w = (const float*)d_in[10];
  const float* wo_b = (const float*)d_in[11];
  const float* rl_w1 = (const float*)d_in[12];
  const float* rl_b1 = (const float*)d_in[13];
  const float* rl_w2 = (const float*)d_in[14];
  const float* rl_b2 = (const float*)d_in[15];
  const float* rl_g  = (const float*)d_in[16];
  const float* rl_be = (const float*)d_in[17];
  const float* pw    = (const float*)d_in[18];
  const float* avec  = (const float*)d_in[19];
  const float* ba    = (const float*)d_in[20];
  float* outf = (float*)d_out;

  // Workspace map (lifetime-based reuse, peak <= 32.5 MB proven)
  char* w = (char*)d_ws;
  short* xbf  = (short*)(w);                              // 0..12M  (dead after QKV gemm)
  short* wT   = (short*)(w + (12u << 20));                // 12..20M; woT (18-20M) lives to end
  short* qh   = (short*)(w + (20u << 20));                // 20..24M (live to pass2)
  short* kh   = (short*)(w + (24u << 20));                // 24..28M (live to pass2)
  short* vh   = (short*)(w + (28u << 20));                // 28..32M (dead after transpose)
  short* qhT  = (short*)(w);                              // 0..4M   (dead after metric_p)
  short* vhT  = (short*)(w + (4u << 20));                 // 4..8M   (live to pass2)
  float* Apart = (float*)(w + (12u << 20));               // 12..14M over wqT (dead after k_res)
  float2* part = (float2*)(w + (8u << 20));               // 8..12M  (pass1 -> sreduce)
  float2* fin  = (float2*)(w + (16u << 20));              // 256KB over wvT (dead after QKV)
  float* avApW = (float*)(w + (16u << 20) + (512u << 10));// 4KB over wvT area
  short* w1T  = (short*)(w + (32u << 20));                // 256KB (live until k_res)
  short* w2T  = (short*)(w + (32u << 20) + (256u << 10)); // 256KB
  short* Hnp0 = (short*)(w);                              // 0..4M  (qhT dead)
  short* Hnp1 = (short*)(w + (12u << 20));                // 12..16M (wqT/wkT/Apart dead)
  short* Hnp2 = (short*)(w + (28u << 20));                // 28..32M (vh dead)
  short* Hnp3 = (short*)(w + (8u << 20));                 // 8..12M  (part dead after sreduce)

  k_cvt_all<<<dim3(7232), 256, 0, stream>>>(q, k, v, wq_w, wk_w, wv_w, wo_w,
                                            rl_w1, rl_w2, xbf, wT, w1T, w2T);
  k_gemm<<<dim3(16, 8, 3), 256, 0, stream>>>(xbf, nullptr, nullptr, nullptr, wT,
                                             wq_b, wk_b, wv_b, qh, nullptr, 0);
  k_transpose<<<dim3(32, 16, 2), 256, 0, stream>>>(qh, vh, qhT, vhT);
  k_metric_p<<<dim3(8, 16), 256, 0, stream>>>(qhT, Apart);
  k_res<<<dim3(16), 512, 0, stream>>>(Apart, w1T, rl_b1, w2T, rl_b2, rl_g, rl_be,
                                      pw, avec, ba, avApW, outf);
  k_pass1<<<dim3(16, 32, 16), 256, 0, stream>>>(qh, kh, avApW, mask, ba, outf, part);
  k_sreduce<<<dim3(128), 256, 0, stream>>>(part, fin);
  k_pass2<<<dim3(16, 4, 16), 256, 0, stream>>>(qh, kh, vhT, avApW, mask, ba, fin,
                                               outf + OFF_ATT, Hnp0, Hnp1, Hnp2, Hnp3);
  k_gemm<<<dim3(16, 8, 1), 256, 0, stream>>>(Hnp0, Hnp1, Hnp2, Hnp3, wT + 3u*D_*D_,
                                             wo_b, wo_b, wo_b, nullptr, outf, 2);
}

// Round 10
// 457.122 us; speedup vs baseline: 1.2034x; 1.0258x over previous
//
#include <hip/hip_runtime.h>
#include <stdint.h>

#define S_ 2048
#define D_ 1024
#define H_ 16
#define DEP_ 64

typedef float f32x4 __attribute__((ext_vector_type(4)));
typedef __bf16 bf16x8 __attribute__((ext_vector_type(8)));

#define MFMA16(a,b,c) __builtin_amdgcn_mfma_f32_16x16x32_bf16((a),(b),(c),0,0,0)

// Output offsets (floats): (out, E, A, pw, attv, ba, avAp, Ep)
static constexpr size_t OFF_E    = 2097152ull;
static constexpr size_t OFF_A    = 69206016ull;
static constexpr size_t OFF_PW   = 69271552ull;
static constexpr size_t OFF_ATT  = 69271616ull;
static constexpr size_t OFF_BA   = 136380480ull;
static constexpr size_t OFF_AVAP = 136380481ull;
static constexpr size_t OFF_EP   = 136381505ull;

__device__ __forceinline__ short f2b(float f) {
  union { float f; uint32_t u; } c; c.f = f;
  uint32_t u = c.u;
  uint32_t r = (u + 0x7fffu + ((u >> 16) & 1u)) >> 16;
  return (short)(r & 0xffffu);
}
__device__ __forceinline__ float b2f(short s) {
  union { uint32_t u; float f; } c; c.u = ((uint32_t)(uint16_t)s) << 16;
  return c.f;
}
__device__ __forceinline__ void st_nt(float* p, f32x4 v) {
  __builtin_nontemporal_store(v, (f32x4*)p);
}

// ---------------- fused converts: inputs, proj weights, res weights ----------------
__global__ void k_cvt_all(const float* __restrict__ q, const float* __restrict__ k,
                          const float* __restrict__ v, const float* __restrict__ wq,
                          const float* __restrict__ wk, const float* __restrict__ wv,
                          const float* __restrict__ wo, const float* __restrict__ w1,
                          const float* __restrict__ w2, short* __restrict__ xbf,
                          short* __restrict__ wT, short* __restrict__ w1T,
                          short* __restrict__ w2T) {
  __shared__ float tile[64][65];
  int bid = blockIdx.x, t = threadIdx.x;
  if (bid < 6144) {
    int z = bid >> 11, bx = bid & 2047;
    const float* src = (z == 0) ? q : (z == 1) ? k : v;
    short* d = xbf + (size_t)z * (S_*D_);
    int i = (bx*256 + t)*4;
    float4 f = *(const float4*)(src + i);
    short4 o;
    o.x = f2b(f.x); o.y = f2b(f.y); o.z = f2b(f.z); o.w = f2b(f.w);
    *(short4*)(d + i) = o;
  } else if (bid < 7168) {
    int u = bid - 6144, z = u >> 8, tl = u & 255;
    int k0 = (tl >> 4)*64, n0 = (tl & 15)*64;
    const float* W = (z == 0) ? wq : (z == 1) ? wk : (z == 2) ? wv : wo;
    short* d = wT + (size_t)z * (D_*D_);
    for (int i = 0; i < 16; ++i) {
      int e = i*256 + t, r = e >> 6, c = e & 63;
      tile[r][c] = W[(size_t)(k0+r)*D_ + n0 + c];
    }
    __syncthreads();
    for (int i = 0; i < 16; ++i) {
      int e = i*256 + t, r = e >> 6, c = e & 63;
      d[(size_t)(n0+r)*D_ + k0 + c] = f2b(tile[c][r]);
    }
  } else {
    int u = bid - 7168, z = u >> 4, bx = u & 15;
    int l = z >> 1, which = z & 1;
    if (which == 0) {
      const float* src = w1 + (size_t)l*65536;
      short* d = w1T + (size_t)l*65536;
      int n0 = bx*64;
      for (int i = 0; i < 16; ++i) {
        int e = i*256 + t, r = e >> 6, c = e & 63;
        tile[r][c] = src[(size_t)r*1024 + n0 + c];
      }
      __syncthreads();
      for (int i = 0; i < 16; ++i) {
        int e = i*256 + t, r = e >> 6, c = e & 63;
        d[(size_t)(n0+r)*64 + c] = f2b(tile[c][r]);
      }
    } else {
      const float* src = w2 + (size_t)l*65536;
      short* d = w2T + (size_t)l*65536;
      int k0 = bx*64;
      for (int i = 0; i < 16; ++i) {
        int e = i*256 + t, r = e >> 6, c = e & 63;
        tile[r][c] = src[(size_t)(k0+r)*64 + c];
      }
      __syncthreads();
      for (int i = 0; i < 16; ++i) {
        int e = i*256 + t, r = e >> 6, c = e & 63;
        d[(size_t)r*1024 + k0 + c] = f2b(tile[c][r]);
      }
    }
  }
}

// ---------------- 128x128 bf16 GEMM: C = X @ WT^T + bias ----------------
// mode 0: write bf16 head-major (LDS-staged); mode 2: X = X+X2+X3+X4 (bf16), write f32 outf
__global__ __launch_bounds__(256) void k_gemm(
    const short* __restrict__ Xall, const short* __restrict__ X2,
    const short* __restrict__ X3, const short* __restrict__ X4,
    const short* __restrict__ WTall,
    const float* __restrict__ b0, const float* __restrict__ b1v,
    const float* __restrict__ b2v, short* __restrict__ dstall,
    float* __restrict__ outf, int mode) {
  __shared__ __align__(16) short SS[2*128*72];   // As/Bs in K-loop; C staging after
  short* As = SS;
  short* Bs = SS + 128*72;
  int z = blockIdx.z;
  const short* X  = Xall + (size_t)z * (S_*D_);
  const short* WT = WTall + (size_t)z * (D_*D_);
  int m0 = blockIdx.x * 128, n0 = blockIdx.y * 128;
  int t = threadIdx.x, lane = t & 63;
  int wr = t >> 7, wc = (t >> 6) & 1;
  int rA = lane & 15, kg = lane >> 4;
  f32x4 acc[4][4] = {};
  for (int kt = 0; kt < 16; ++kt) {
#pragma unroll
    for (int i = 0; i < 4; ++i) {
      int cid = i*256 + t, row = cid >> 3, c = cid & 7;
      size_t xi = (size_t)(m0+row)*D_ + kt*64 + c*8;
      if (mode == 2) {
        union { int4 v; short s[8]; } a1, a2, a3, a4, o;
        a1.v = *(const int4*)&X[xi];
        a2.v = *(const int4*)&X2[xi];
        a3.v = *(const int4*)&X3[xi];
        a4.v = *(const int4*)&X4[xi];
#pragma unroll
        for (int j = 0; j < 8; ++j)
          o.s[j] = f2b(b2f(a1.s[j]) + b2f(a2.s[j]) + b2f(a3.s[j]) + b2f(a4.s[j]));
        *(int4*)&As[row*72 + c*8] = o.v;
      } else {
        *(int4*)&As[row*72 + c*8] = *(const int4*)&X[xi];
      }
      *(int4*)&Bs[row*72 + c*8] = *(const int4*)&WT[(size_t)(n0+row)*D_ + kt*64 + c*8];
    }
    __syncthreads();
#pragma unroll
    for (int kk = 0; kk < 2; ++kk) {
      bf16x8 a[4], b[4];
#pragma unroll
      for (int m = 0; m < 4; ++m)
        a[m] = *(const bf16x8*)&As[(wr*64 + m*16 + rA)*72 + kk*32 + kg*8];
#pragma unroll
      for (int n = 0; n < 4; ++n)
        b[n] = *(const bf16x8*)&Bs[(wc*64 + n*16 + rA)*72 + kk*32 + kg*8];
#pragma unroll
      for (int m = 0; m < 4; ++m)
#pragma unroll
        for (int n = 0; n < 4; ++n)
          acc[m][n] = MFMA16(a[m], b[n], acc[m][n]);
    }
    __syncthreads();
  }
  const float* bias = (mode != 0) ? b0 : (z == 0 ? b0 : (z == 1 ? b1v : b2v));
  if (mode == 0) {
    short* Ct = SS;
#pragma unroll
    for (int m = 0; m < 4; ++m)
#pragma unroll
      for (int n = 0; n < 4; ++n) {
        int col = wc*64 + n*16 + rA;
        float bb = bias[n0 + col];
#pragma unroll
        for (int rr = 0; rr < 4; ++rr) {
          int row = wr*64 + m*16 + kg*4 + rr;
          Ct[row*136 + col] = f2b(acc[m][n][rr] + bb);
        }
      }
    __syncthreads();
#pragma unroll
    for (int p = 0; p < 8; ++p) {
      int row = p*16 + (t >> 4), unit = t & 15;
      int4 vv = *(const int4*)&Ct[row*136 + unit*8];
      int gcol = n0 + unit*8;
      int head = gcol >> 6, dd = gcol & 63;
      *(int4*)&dstall[(size_t)z*(S_*D_) + ((size_t)head*S_ + m0 + row)*DEP_ + dd] = vv;
    }
  } else {
    float* Ct = (float*)SS;
#pragma unroll
    for (int half = 0; half < 2; ++half) {
      if (wr == half) {
#pragma unroll
        for (int m = 0; m < 4; ++m)
#pragma unroll
          for (int n = 0; n < 4; ++n) {
            int col = wc*64 + n*16 + rA;
            float bb = bias[n0 + col];
#pragma unroll
            for (int rr = 0; rr < 4; ++rr)
              Ct[(m*16 + kg*4 + rr)*132 + col] = acc[m][n][rr] + bb;
          }
      }
      __syncthreads();
#pragma unroll
      for (int p = 0; p < 8; ++p) {
        int row_l = p*8 + (t >> 5), unit = t & 31;
        f32x4 vv = *(const f32x4*)&Ct[row_l*132 + unit*4];
        st_nt(&outf[(size_t)(m0 + half*64 + row_l)*D_ + n0 + unit*4], vv);
      }
      __syncthreads();
    }
  }
}

// ---------------- bf16 transpose [h][S][64] -> [h][64][S] ----------------
__global__ void k_transpose(const short* __restrict__ qh, const short* __restrict__ vh,
                            short* __restrict__ qhT, short* __restrict__ vhT) {
  __shared__ short tile[64][68];
  const short* src = blockIdx.z ? vh : qh;
  short* dst = blockIdx.z ? vhT : qhT;
  int h = blockIdx.y, s0 = blockIdx.x * 64, t = threadIdx.x;
  for (int i = 0; i < 16; ++i) {
    int e = i*256 + t, r = e >> 6, c = e & 63;
    tile[r][c] = src[((size_t)h*S_ + s0 + r)*DEP_ + c];
  }
  __syncthreads();
  for (int i = 0; i < 16; ++i) {
    int e = i*256 + t, r = e >> 6, c = e & 63;
    dst[((size_t)h*DEP_ + r)*S_ + s0 + c] = tile[c][r];
  }
}

// ---------------- metric partial ----------------
__global__ __launch_bounds__(256) void k_metric_p(const short* __restrict__ qhT,
                                                  float* __restrict__ Apart) {
  __shared__ short qt[64*72];
  int kc = blockIdx.x, h = blockIdx.y, t = threadIdx.x, lane = t & 63;
  int wr = t >> 7, wc = (t >> 6) & 1;
  int rA = lane & 15, kg = lane >> 4;
  f32x4 acc[2][2] = {};
  for (int kt = 0; kt < 4; ++kt) {
#pragma unroll
    for (int i = 0; i < 2; ++i) {
      int cid = i*256 + t, row = cid >> 3, c = cid & 7;
      *(int4*)&qt[row*72 + c*8] =
        *(const int4*)&qhT[((size_t)h*DEP_ + row)*S_ + kc*256 + kt*64 + c*8];
    }
    __syncthreads();
#pragma unroll
    for (int kk = 0; kk < 2; ++kk) {
      bf16x8 a[2], b[2];
#pragma unroll
      for (int m = 0; m < 2; ++m)
        a[m] = *(const bf16x8*)&qt[(wr*32 + m*16 + rA)*72 + kk*32 + kg*8];
#pragma unroll
      for (int n = 0; n < 2; ++n)
        b[n] = *(const bf16x8*)&qt[(wc*32 + n*16 + rA)*72 + kk*32 + kg*8];
#pragma unroll
      for (int m = 0; m < 2; ++m)
#pragma unroll
        for (int n = 0; n < 2; ++n)
          acc[m][n] = MFMA16(a[m], b[n], acc[m][n]);
    }
    __syncthreads();
  }
#pragma unroll
  for (int m = 0; m < 2; ++m)
#pragma unroll
    for (int n = 0; n < 2; ++n)
#pragma unroll
      for (int rr = 0; rr < 4; ++rr) {
        int row = wr*32 + m*16 + kg*4 + rr, col = wc*32 + n*16 + rA;
        Apart[((size_t)(kc*16 + h))*4096 + row*64 + col] = acc[m][n][rr];
      }
}

// ---------------- fused res stack: metric reduce + 2x(d1+d2+LN) + avAp ----------------
__global__ __launch_bounds__(512) void k_res(
    const float* __restrict__ Apart, const short* __restrict__ w1T,
    const float* __restrict__ b1, const short* __restrict__ w2T,
    const float* __restrict__ b2, const float* __restrict__ gl,
    const float* __restrict__ bel, const float* __restrict__ pwv,
    const float* __restrict__ av, const float* __restrict__ bav,
    float* __restrict__ avApW, float* __restrict__ outB) {
  __shared__ float Af[64][68];
  __shared__ short Afb[64][72];
  __shared__ short hdP[64*520];
  __shared__ float red[8][64];
  int h = blockIdx.x, t = threadIdx.x;
  int lane = t & 63, w = t >> 6;
  int rA = lane & 15, kg = lane >> 4;
#pragma unroll
  for (int i = 0; i < 2; ++i) {
    int idx = (i*512 + t)*4;
    f32x4 s = {};
#pragma unroll
    for (int kc = 0; kc < 8; ++kc)
      s += *(const f32x4*)&Apart[((size_t)(kc*16 + h))*4096 + idx];
    int r = idx >> 6, c = idx & 63;
    *(f32x4*)&Af[r][c] = s;
    union { int2 v; short sh[4]; } pk;
#pragma unroll
    for (int j = 0; j < 4; ++j) pk.sh[j] = f2b(s[j]);
    *(int2*)&Afb[r][c] = pk.v;
  }
  __syncthreads();
  for (int layer = 0; layer < 2; ++layer) {
    const short* w1l = w1T + layer*65536;
    const short* w2l = w2T + layer*65536;
    f32x4 acc2[4][4] = {};
    for (int kc = 0; kc < 2; ++kc) {
      int c0g = kc*512 + w*64;
      f32x4 acc1[4][4] = {};
#pragma unroll
      for (int kk = 0; kk < 2; ++kk) {
        bf16x8 aA[4], bW[4];
#pragma unroll
        for (int mf = 0; mf < 4; ++mf)
          aA[mf] = *(const bf16x8*)&Afb[mf*16 + rA][kk*32 + kg*8];
#pragma unroll
        for (int nf = 0; nf < 4; ++nf)
          bW[nf] = *(const bf16x8*)&w1l[(size_t)(c0g + nf*16 + rA)*64 + kk*32 + kg*8];
#pragma unroll
        for (int mf = 0; mf < 4; ++mf)
#pragma unroll
          for (int nf = 0; nf < 4; ++nf)
            acc1[mf][nf] = MFMA16(aA[mf], bW[nf], acc1[mf][nf]);
      }
      __syncthreads();
#pragma unroll
      for (int nf = 0; nf < 4; ++nf) {
        int col = w*64 + nf*16 + rA;
        float bb1 = b1[layer*1024 + kc*512 + col];
#pragma unroll
        for (int mf = 0; mf < 4; ++mf)
#pragma unroll
          for (int rr = 0; rr < 4; ++rr) {
            int r = mf*16 + kg*4 + rr;
            hdP[r*520 + col] = f2b(fmaxf(acc1[mf][nf][rr] + bb1, 0.f));
          }
      }
      __syncthreads();
#pragma unroll
      for (int kk = 0; kk < 2; ++kk) {
        bf16x8 a2[4], bw2[4];
#pragma unroll
        for (int mf = 0; mf < 4; ++mf)
          a2[mf] = *(const bf16x8*)&hdP[(mf*16 + rA)*520 + w*64 + kk*32 + kg*8];
#pragma unroll
        for (int nf = 0; nf < 4; ++nf)
          bw2[nf] = *(const bf16x8*)&w2l[(size_t)(nf*16 + rA)*1024 + kc*512 + w*64 + kk*32 + kg*8];
#pragma unroll
        for (int mf = 0; mf < 4; ++mf)
#pragma unroll
          for (int nf = 0; nf < 4; ++nf)
            acc2[mf][nf] = MFMA16(a2[mf], bw2[nf], acc2[mf][nf]);
      }
    }
    __syncthreads();
    float* P = (float*)hdP;
    if (w >= 4) {
      int slot = w - 4;
#pragma unroll
      for (int mf = 0; mf < 4; ++mf)
#pragma unroll
        for (int nf = 0; nf < 4; ++nf)
#pragma unroll
          for (int rr = 0; rr < 4; ++rr)
            P[slot*4160 + (mf*16 + kg*4 + rr)*65 + nf*16 + rA] = acc2[mf][nf][rr];
    }
    __syncthreads();
    if (w < 4) {
#pragma unroll
      for (int mf = 0; mf < 4; ++mf)
#pragma unroll
        for (int nf = 0; nf < 4; ++nf)
#pragma unroll
          for (int rr = 0; rr < 4; ++rr)
            P[w*4160 + (mf*16 + kg*4 + rr)*65 + nf*16 + rA] += acc2[mf][nf][rr];
    }
    __syncthreads();
    int r = t >> 3, j0 = (t & 7)*8;
    float x[8], s1 = 0.f, s2 = 0.f;
#pragma unroll
    for (int j = 0; j < 8; ++j) {
      int c = j0 + j;
      float xx = P[r*65 + c] + P[4160 + r*65 + c] + P[8320 + r*65 + c] + P[12480 + r*65 + c]
               + b2[layer*64 + c] + Af[r][c];
      x[j] = xx; s1 += xx; s2 += xx*xx;
    }
    s1 += __shfl_xor(s1, 1); s1 += __shfl_xor(s1, 2); s1 += __shfl_xor(s1, 4);
    s2 += __shfl_xor(s2, 1); s2 += __shfl_xor(s2, 2); s2 += __shfl_xor(s2, 4);
    float mean = s1 * (1.f/64.f);
    float var  = s2 * (1.f/64.f) - mean*mean;
    float rstd = rsqrtf(var + 1e-6f);
#pragma unroll
    for (int j = 0; j < 8; ++j) {
      int c = j0 + j;
      float nx = (x[j] - mean)*rstd*gl[layer*64 + c] + bel[layer*64 + c];
      Af[r][c] = nx;
      Afb[r][c] = f2b(nx);
      if (layer == 1) outB[OFF_A + (size_t)h*4096 + r*64 + c] = nx;
    }
    __syncthreads();
  }
  {
    int e = t & 63, dg = t >> 6;
    float pe = pwv[e], p = 0.f;
#pragma unroll
    for (int j = 0; j < 8; ++j) {
      int d = dg*8 + j;
      p += av[d] * powf(fabsf(Af[d][e]) + 1e-9f, pe);
    }
    red[dg][e] = p;
  }
  __syncthreads();
  if (t < 64) {
    float tot = 0.f;
#pragma unroll
    for (int g = 0; g < 8; ++g) tot += red[g][t];
    avApW[h*64 + t] = tot;
    outB[OFF_AVAP + h*64 + t] = tot;
  }
  if (h == 0) {
    if (t < 64) outB[OFF_PW + t] = pwv[t];
    if (t == 0) outB[OFF_BA] = bav[0];
  }
}

// ---------------- pass1: 64-row tiles, E/Ep staged nt stores + per-tile stats ----------------
__global__ __launch_bounds__(256) void k_pass1(
    const short* __restrict__ qh, const short* __restrict__ kh,
    const float* __restrict__ avAp, const float* __restrict__ mask,
    const float* __restrict__ bap, float* __restrict__ outB,
    float2* __restrict__ part) {
  __shared__ float Et[64*128];     // 32KB union: Qs(8K)+Ks(16K) | E f32 tile
  __shared__ float2 red[4][64];
  __shared__ float avl[64];
  short* Qs = (short*)Et;          // [0, 8K)
  short* Ks = ((short*)Et) + 4096; // [8K, 24K)
  int tt = blockIdx.x, sb = blockIdx.y, h = blockIdx.z;
  int s0 = sb*64, t0 = tt*128;
  int t = threadIdx.x, lane = t & 63, w = t >> 6;
  int rA = lane & 15, kg = lane >> 4;
  if (t < 16) *(f32x4*)&avl[t*4] = *(const f32x4*)&avAp[h*64 + t*4];
  __syncthreads();
#pragma unroll
  for (int i = 0; i < 6; ++i) {
    int cid = i*256 + t, row = cid >> 3, c = cid & 7, cs = c ^ (row & 7);
    if (row < 64) {
      union { int4 v; short s[8]; } qa, qo;
      qa.v = *(const int4*)&qh[((size_t)h*S_ + s0 + row)*DEP_ + c*8];
#pragma unroll
      for (int j = 0; j < 8; ++j) qo.s[j] = f2b(b2f(qa.s[j]) * avl[c*8 + j]);
      *(int4*)&Qs[row*64 + cs*8] = qo.v;
    } else {
      int kr = row - 64, csk = c ^ (kr & 7);
      *(int4*)&Ks[kr*64 + csk*8] = *(const int4*)&kh[((size_t)h*S_ + t0 + kr)*DEP_ + c*8];
    }
  }
  __syncthreads();
  f32x4 acc[4][2] = {};
#pragma unroll
  for (int kk = 0; kk < 2; ++kk) {
    bf16x8 a[4], b[2];
#pragma unroll
    for (int m = 0; m < 4; ++m) {
      int row = m*16 + rA, c = (kk*4 + kg) ^ (row & 7);
      a[m] = *(const bf16x8*)&Qs[row*64 + c*8];
    }
#pragma unroll
    for (int n = 0; n < 2; ++n) {
      int kr = w*32 + n*16 + rA, c = (kk*4 + kg) ^ (kr & 7);
      b[n] = *(const bf16x8*)&Ks[kr*64 + c*8];
    }
#pragma unroll
    for (int m = 0; m < 4; ++m)
#pragma unroll
      for (int n = 0; n < 2; ++n)
        acc[m][n] = MFMA16(b[n], a[m], acc[m][n]);   // row=m*16+rA, col=w*32+n*16+kg*4+j
  }
  float bav = bap[0];
  f32x4 mkf[2];
#pragma unroll
  for (int n = 0; n < 2; ++n) {
    f32x4 mm = *(const f32x4*)&mask[t0 + w*32 + n*16 + kg*4];
#pragma unroll
    for (int j = 0; j < 4; ++j) mkf[n][j] = mm[j] * (-1e9f);
  }
#pragma unroll
  for (int m = 0; m < 4; ++m) {
    float mx = -3.4e38f;
    f32x4 ep4[2];
#pragma unroll
    for (int n = 0; n < 2; ++n) {
      f32x4 e = acc[m][n];
      f32x4 ep;
#pragma unroll
      for (int j = 0; j < 4; ++j) {
        float ee = e[j];
        ep[j] = (ee > 0.f ? ee : 0.2f*ee) + bav + mkf[n][j];
        mx = fmaxf(mx, ep[j]);
      }
      ep4[n] = ep;
    }
    mx = fmaxf(mx, __shfl_xor(mx, 16));
    mx = fmaxf(mx, __shfl_xor(mx, 32));
    float sm = 0.f;
#pragma unroll
    for (int n = 0; n < 2; ++n)
#pragma unroll
      for (int j = 0; j < 4; ++j) sm += expf(ep4[n][j] - mx);
    sm += __shfl_xor(sm, 16);
    sm += __shfl_xor(sm, 32);
    if (kg == 0) red[w][m*16 + rA] = make_float2(mx, sm);
  }
  __syncthreads();
  if (t < 64) {
    float M = red[0][t].x;
#pragma unroll
    for (int g = 1; g < 4; ++g) M = fmaxf(M, red[g][t].x);
    float L = 0.f;
#pragma unroll
    for (int g = 0; g < 4; ++g) L += red[g][t].y * expf(red[g][t].x - M);
    part[((size_t)(h*S_ + s0 + t))*16 + tt] = make_float2(M, L);
  }
#pragma unroll
  for (int m = 0; m < 4; ++m)
#pragma unroll
    for (int n = 0; n < 2; ++n) {
      int row = m*16 + rA;
      int unit = w*8 + n*4 + kg;
      *(f32x4*)&Et[row*128 + ((unit ^ (row & 7)))*4] = acc[m][n];
    }
  __syncthreads();
  float* Eo  = outB + OFF_E;
  float* Epo = outB + OFF_EP;
  int colu = t & 31, rbase = t >> 5;
  f32x4 mm4 = *(const f32x4*)&mask[t0 + colu*4];
  f32x4 mk4;
#pragma unroll
  for (int j = 0; j < 4; ++j) mk4[j] = mm4[j] * (-1e9f);
#pragma unroll
  for (int r = 0; r < 8; ++r) {
    int row = r*8 + rbase;
    f32x4 e = *(const f32x4*)&Et[row*128 + ((colu ^ (row & 7)))*4];
    size_t gb = ((size_t)h*S_ + s0 + row)*S_ + t0 + colu*4;
    st_nt(&Eo[gb], e);
    f32x4 ep;
#pragma unroll
    for (int j = 0; j < 4; ++j)
      ep[j] = (e[j] > 0.f ? e[j] : 0.2f*e[j]) + bav + mk4[j];
    st_nt(&Epo[gb], ep);
  }
}

// ---------------- softmax stats reduce ----------------
__global__ void k_sreduce(const float2* __restrict__ part, float2* __restrict__ fin) {
  int row = blockIdx.x * 256 + threadIdx.x;
  const float2* pp = part + (size_t)row * 16;
  float2 p[16];
  float M = -3.4e38f;
#pragma unroll
  for (int i = 0; i < 16; ++i) { p[i] = pp[i]; M = fmaxf(M, p[i].x); }
  float L = 0.f;
#pragma unroll
  for (int i = 0; i < 16; ++i) L += p[i].y * expf(p[i].x - M);
  fin[row] = make_float2(M, L);
}

// ---------------- pass2: attv (full-line nt) + PV partial (staged Hn), tc=4 ----------------
__global__ __launch_bounds__(256) void k_pass2(
    const short* __restrict__ qh, const short* __restrict__ kh,
    const short* __restrict__ vhT, const float* __restrict__ avAp,
    const float* __restrict__ mask, const float* __restrict__ bap,
    const float2* __restrict__ fin, float* __restrict__ attv,
    short* __restrict__ Hnp0, short* __restrict__ Hnp1,
    short* __restrict__ Hnp2, short* __restrict__ Hnp3) {
  __shared__ short Qs[128*64];
  __shared__ __align__(16) short KP[128*128]; // kh tile / P tile (swz) / Hn staging
  __shared__ short Vs[64*128];
  __shared__ float avl[64];
  int st = blockIdx.x, tc = blockIdx.y, h = blockIdx.z;
  int s0 = st * 128;
  int t = threadIdx.x, lane = t & 63;
  int wr = t >> 7, wc = (t >> 6) & 1;
  int rA = lane & 15, kg = lane >> 4;
  if (t < 16) *(f32x4*)&avl[t*4] = *(const f32x4*)&avAp[h*64 + t*4];
  __syncthreads();
#pragma unroll
  for (int i = 0; i < 4; ++i) {
    int cid = i*256 + t, row = cid >> 3, c = cid & 7, cs = c ^ (row & 7);
    union { int4 v; short s[8]; } qa, qo;
    qa.v = *(const int4*)&qh[((size_t)h*S_ + s0 + row)*DEP_ + c*8];
#pragma unroll
    for (int j = 0; j < 8; ++j) qo.s[j] = f2b(b2f(qa.s[j]) * avl[c*8 + j]);
    *(int4*)&Qs[row*64 + cs*8] = qo.v;
  }
  float Ms[4], Li[4];
#pragma unroll
  for (int m = 0; m < 4; ++m) {
    float2 f = fin[h*S_ + s0 + wr*64 + m*16 + rA];
    Ms[m] = f.x; Li[m] = 1.f / f.y;
  }
  float bav = bap[0];
  __syncthreads();
  bf16x8 aq[4][2];
#pragma unroll
  for (int m = 0; m < 4; ++m)
#pragma unroll
    for (int kk = 0; kk < 2; ++kk) {
      int row = wr*64 + m*16 + rA, c = (kk*4 + kg) ^ (row & 7);
      aq[m][kk] = *(const bf16x8*)&Qs[row*64 + c*8];
    }
  f32x4 acc2[4][2] = {};
  for (int tt = tc*4; tt < tc*4 + 4; ++tt) {
    int t0 = tt * 128;
    __syncthreads();    // prev iteration's P/attv/V reads done
#pragma unroll
    for (int i = 0; i < 4; ++i) {
      int cid = i*256 + t, row = cid >> 3, c = cid & 7, cs = c ^ (row & 7);
      *(int4*)&KP[row*64 + cs*8] = *(const int4*)&kh[((size_t)h*S_ + t0 + row)*DEP_ + c*8];
    }
#pragma unroll
    for (int i = 0; i < 4; ++i) {
      int cid = i*256 + t, row = cid >> 4, c = cid & 15, cs = c ^ (row & 7);
      *(int4*)&Vs[row*128 + cs*8] = *(const int4*)&vhT[((size_t)h*DEP_ + row)*S_ + t0 + c*8];
    }
    __syncthreads();
    f32x4 accE[4][4] = {};
#pragma unroll
    for (int kk = 0; kk < 2; ++kk) {
      bf16x8 b[4];
#pragma unroll
      for (int n = 0; n < 4; ++n) {
        int row = wc*64 + n*16 + rA, c = (kk*4 + kg) ^ (row & 7);
        b[n] = *(const bf16x8*)&KP[row*64 + c*8];
      }
#pragma unroll
      for (int m = 0; m < 4; ++m)
#pragma unroll
        for (int n = 0; n < 4; ++n)
          accE[m][n] = MFMA16(b[n], aq[m][kk], accE[m][n]);   // swapped
    }
    f32x4 mkf[4];
#pragma unroll
    for (int n = 0; n < 4; ++n) {
      f32x4 mm = *(const f32x4*)&mask[t0 + wc*64 + n*16 + kg*4];
#pragma unroll
      for (int j = 0; j < 4; ++j) mkf[n][j] = mm[j] * (-1e9f);
    }
#pragma unroll
    for (int m = 0; m < 4; ++m)
#pragma unroll
      for (int n = 0; n < 4; ++n) {
        f32x4 e = accE[m][n], p;
#pragma unroll
        for (int j = 0; j < 4; ++j) {
          float ep = (e[j] > 0.f ? e[j] : 0.2f*e[j]) + bav + mkf[n][j];
          p[j] = expf(ep - Ms[m]) * Li[m];
        }
        accE[m][n] = p;
      }
    __syncthreads();    // all KP(kh) fragment reads done before P overwrites
#pragma unroll
    for (int m = 0; m < 4; ++m) {
      int srow = wr*64 + m*16 + rA;
#pragma unroll
      for (int n = 0; n < 4; ++n) {
        int tcol = wc*64 + n*16 + kg*4;
        union { int2 v; short s[4]; } pk;
#pragma unroll
        for (int j = 0; j < 4; ++j) pk.s[j] = f2b(accE[m][n][j]);
        *(int2*)((char*)KP + srow*256 + ((tcol*2) ^ ((srow & 7) << 4))) = pk.v;
      }
    }
    __syncthreads();
#pragma unroll
    for (int kkp = 0; kkp < 4; ++kkp) {
      bf16x8 ap[4], bv[2];
#pragma unroll
      for (int m = 0; m < 4; ++m) {
        int row = wr*64 + m*16 + rA;
        ap[m] = *(const bf16x8*)((const char*)KP + row*256 + ((kkp*64 + kg*16) ^ ((row & 7) << 4)));
      }
#pragma unroll
      for (int n = 0; n < 2; ++n) {
        int dd = wc*32 + n*16 + rA, c = (kkp*4 + kg) ^ (dd & 7);
        bv[n] = *(const bf16x8*)&Vs[dd*128 + c*8];
      }
#pragma unroll
      for (int m = 0; m < 4; ++m)
#pragma unroll
        for (int n = 0; n < 2; ++n)
          acc2[m][n] = MFMA16(ap[m], bv[n], acc2[m][n]);
    }
    // attv store: full-line nt (each wave: 2 rows x 512B contiguous per instr)
#pragma unroll
    for (int it = 0; it < 16; ++it) {
      int row = it*8 + (t >> 5);
      int u8 = t & 31;
      union { int2 v; short s[4]; } pv;
      pv.v = *(const int2*)((const char*)KP + row*256 + ((u8*8) ^ ((row & 7) << 4)));
      f32x4 o;
#pragma unroll
      for (int j = 0; j < 4; ++j) o[j] = b2f(pv.s[j]);
      st_nt(&attv[((size_t)h*S_ + s0 + row)*S_ + t0 + u8*4], o);
    }
  }
  // stage Hn tile into KP, then coalesced stores
  short* Hp = (tc == 0) ? Hnp0 : (tc == 1) ? Hnp1 : (tc == 2) ? Hnp2 : Hnp3;
  short* Ht = KP;
  __syncthreads();
#pragma unroll
  for (int m = 0; m < 4; ++m)
#pragma unroll
    for (int n = 0; n < 2; ++n) {
      int col = wc*32 + n*16 + rA;
#pragma unroll
      for (int rr = 0; rr < 4; ++rr) {
        int row = wr*64 + m*16 + kg*4 + rr;
        Ht[row*72 + col] = f2b(acc2[m][n][rr]);
      }
    }
  __syncthreads();
#pragma unroll
  for (int p = 0; p < 4; ++p) {
    int row = p*32 + (t >> 3), unit = t & 7;
    int4 vv = *(const int4*)&Ht[row*72 + unit*8];
    *(int4*)&Hp[(size_t)(s0 + row)*D_ + h*DEP_ + unit*8] = vv;
  }
}

extern "C" void kernel_launch(void* const* d_in, const int* in_sizes, int n_in,
                              void* d_out, int out_size, void* d_ws, size_t ws_size,
                              hipStream_t stream) {
  (void)in_sizes; (void)n_in; (void)out_size; (void)ws_size;
  const float* q    = (const float*)d_in[0];
  const float* k    = (const float*)d_in[1];
  const float* v    = (const float*)d_in[2];
  const float* mask = (const float*)d_in[3];
  const float* wq_w = (const float*)d_in[4];
  const float* wq_b = (const float*)d_in[5];
  const float* wk_w = (const float*)d_in[6];
  const float* wk_b = (const float*)d_in[7];
  const float* wv_w = (const float*)d_in[8];
  const float* wv_b = (const float*)d_in[9];
  const float* wo_w = (const float*)d_in[10];
  const float* wo_b = (const float*)d_in[11];
  const float* rl_w1 = (const float*)d_in[12];
  const float* rl_b1 = (const float*)d_in[13];
  const float* rl_w2 = (const float*)d_in[14];
  const float* rl_b2 = (const float*)d_in[15];
  const float* rl_g  = (const float*)d_in[16];
  const float* rl_be = (const float*)d_in[17];
  const float* pw    = (const float*)d_in[18];
  const float* avec  = (const float*)d_in[19];
  const float* ba    = (const float*)d_in[20];
  float* outf = (float*)d_out;

  // Workspace map (lifetime-based reuse, peak <= 32.5 MB proven)
  char* w = (char*)d_ws;
  short* xbf  = (short*)(w);                              // 0..12M  (dead after QKV gemm)
  short* wT   = (short*)(w + (12u << 20));                // 12..20M; woT (18-20M) lives to end
  short* qh   = (short*)(w + (20u << 20));                // 20..24M (live to pass2)
  short* kh   = (short*)(w + (24u << 20));                // 24..28M (live to pass2)
  short* vh   = (short*)(w + (28u << 20));                // 28..32M (dead after transpose)
  short* qhT  = (short*)(w);                              // 0..4M   (dead after metric_p)
  short* vhT  = (short*)(w + (4u << 20));                 // 4..8M   (live to pass2)
  float* Apart = (float*)(w + (12u << 20));               // 12..14M over wqT (dead after k_res)
  float2* part = (float2*)(w + (8u << 20));               // 8..12M  (pass1 -> sreduce)
  float2* fin  = (float2*)(w + (16u << 20));              // 256KB over wvT (dead after QKV)
  float* avApW = (float*)(w + (16u << 20) + (512u << 10));// 4KB over wvT area
  short* w1T  = (short*)(w + (32u << 20));                // 256KB (live until k_res)
  short* w2T  = (short*)(w + (32u << 20) + (256u << 10)); // 256KB
  short* Hnp0 = (short*)(w);                              // 0..4M  (qhT dead)
  short* Hnp1 = (short*)(w + (12u << 20));                // 12..16M (wqT/wkT/Apart dead)
  short* Hnp2 = (short*)(w + (28u << 20));                // 28..32M (vh dead)
  short* Hnp3 = (short*)(w + (8u << 20));                 // 8..12M  (part dead after sreduce)

  k_cvt_all<<<dim3(7232), 256, 0, stream>>>(q, k, v, wq_w, wk_w, wv_w, wo_w,
                                            rl_w1, rl_w2, xbf, wT, w1T, w2T);
  k_gemm<<<dim3(16, 8, 3), 256, 0, stream>>>(xbf, nullptr, nullptr, nullptr, wT,
                                             wq_b, wk_b, wv_b, qh, nullptr, 0);
  k_transpose<<<dim3(32, 16, 2), 256, 0, stream>>>(qh, vh, qhT, vhT);
  k_metric_p<<<dim3(8, 16), 256, 0, stream>>>(qhT, Apart);
  k_res<<<dim3(16), 512, 0, stream>>>(Apart, w1T, rl_b1, w2T, rl_b2, rl_g, rl_be,
                                      pw, avec, ba, avApW, outf);
  k_pass1<<<dim3(16, 32, 16), 256, 0, stream>>>(qh, kh, avApW, mask, ba, outf, part);
  k_sreduce<<<dim3(128), 256, 0, stream>>>(part, fin);
  k_pass2<<<dim3(16, 4, 16), 256, 0, stream>>>(qh, kh, vhT, avApW, mask, ba, fin,
                                               outf + OFF_ATT, Hnp0, Hnp1, Hnp2, Hnp3);
  k_gemm<<<dim3(16, 8, 1), 256, 0, stream>>>(Hnp0, Hnp1, Hnp2, Hnp3, wT + 3u*D_*D_,
                                             wo_b, wo_b, wo_b, nullptr, outf, 2);
}